// Round 1
// baseline (8099.625 us; speedup 1.0000x reference)
//
#include <hip/hip_runtime.h>
#include <math.h>

namespace {

constexpr int BSZ  = 1024;
constexpr int P    = 128;
constexpr int S    = 128;
constexpr int HG   = 128;
constexpr int NH   = 4;
constexpr int N    = 168;     // P + IND
constexpr int CB   = 64;      // batch chunk for attention phase
constexpr int CHUNK_QKV = CB * NH * N * HG;   // floats per Q (or K or V) chunk

// ---------- block reductions ----------
__device__ __forceinline__ float rsum128(float v, volatile float* red2){
  #pragma unroll
  for (int o = 32; o > 0; o >>= 1) v += __shfl_down(v, o, 64);
  __syncthreads();
  if ((threadIdx.x & 63) == 0) red2[threadIdx.x >> 6] = v;
  __syncthreads();
  return red2[0] + red2[1];
}
__device__ __forceinline__ float rmax128(float v, volatile float* red2){
  #pragma unroll
  for (int o = 32; o > 0; o >>= 1) v = fmaxf(v, __shfl_down(v, o, 64));
  __syncthreads();
  if ((threadIdx.x & 63) == 0) red2[threadIdx.x >> 6] = v;
  __syncthreads();
  return fmaxf(red2[0], red2[1]);
}
__device__ __forceinline__ float rmin128(float v, volatile float* red2){
  #pragma unroll
  for (int o = 32; o > 0; o >>= 1) v = fminf(v, __shfl_down(v, o, 64));
  __syncthreads();
  if ((threadIdx.x & 63) == 0) red2[threadIdx.x >> 6] = v;
  __syncthreads();
  return fminf(red2[0], red2[1]);
}
__device__ __forceinline__ float rsum256(float v, volatile float* red4){
  #pragma unroll
  for (int o = 32; o > 0; o >>= 1) v += __shfl_down(v, o, 64);
  __syncthreads();
  if ((threadIdx.x & 63) == 0) red4[threadIdx.x >> 6] = v;
  __syncthreads();
  return red4[0] + red4[1] + red4[2] + red4[3];
}

// ---------- K1: per-patch features (temporal + DFT) ----------
// one block (128 threads) per patch; writes 20 raw feature cols into Xf[...,0:20]
__global__ __launch_bounds__(128) void feat_kernel(const float* __restrict__ X,
                                                   float* __restrict__ Xf){
  const int pp = blockIdx.x;       // b*128 + p
  const int t  = threadIdx.x;      // 0..127
  __shared__ float  sv[128];
  __shared__ float2 tw[128];       // exp(-2*pi*i*m/128), conjugate-symmetric by construction
  __shared__ float  psd_s[128];
  __shared__ float  red2[2];

  float x = X[pp * 128 + t];
  sv[t] = x;
  if (t <= 64){
    double ang = 6.283185307179586476925286766559 * (double)t / 128.0;
    tw[t] = make_float2(cosf((float)ang), -sinf((float)ang));
  }
  __syncthreads();
  if (t >= 65){
    float2 w = tw[128 - t];        // exact conjugate mirror -> bitwise-symmetric psd
    tw[t] = make_float2(w.x, -w.y);
  }

  // temporal features
  float mx    = rmax128(x, red2);
  float mn    = rmin128(x, red2);
  float mean  = rsum128(x, red2) * (1.0f / 128.0f);
  float sumsq = rsum128(x * x, red2);
  float cen = x - mean;
  float c2  = cen * cen;
  float m2  = rsum128(c2, red2);
  float m3  = rsum128(c2 * cen, red2);
  float m4  = rsum128(c2 * c2, red2);
  float var = m2 * (1.0f / 127.0f);
  float sd  = sqrtf(var);
  float rms = sqrtf(sumsq * (1.0f / 128.0f));
  float ex  = expf(x - mx);
  float Z   = rsum128(ex, red2);
  float SxE = rsum128(ex * x, red2);
  float ent = (mx + logf(Z)) - SxE / Z;
  const float lo = (float)(-1.0 + 1e-7), hi = (float)(1.0 - 1e-7);
  float aa = asinf(fminf(fmaxf(x, lo), hi));
  float amean = rsum128(aa, red2) * (1.0f / 128.0f);
  float ad = aa - amean;
  float std_asin = sqrtf(rsum128(ad * ad, red2) * (1.0f / 127.0f));
  float bb = atanf(x);
  float bmean = rsum128(bb, red2) * (1.0f / 128.0f);
  float bd = bb - bmean;
  float std_atan = sqrtf(rsum128(bd * bd, red2) * (1.0f / 127.0f));
  float kurt = (m4 * (1.0f / 128.0f)) / (sd * sd * sd * sd) - 3.0f;
  float skew = (m3 * (1.0f / 128.0f)) / (sd * sd * sd);

  // DFT bin k = t   (fv[128-k] == conj(fv[k]) bitwise given symmetric table)
  float re = 0.f, im = 0.f;
  int idx = 0;
  for (int tt = 0; tt < 128; ++tt){
    float s0 = sv[tt];
    float2 w = tw[idx];
    re = fmaf(s0, w.x, re);
    im = fmaf(s0, w.y, im);
    idx = (idx + t) & 127;
  }
  float a2  = re * re + im * im;
  float psd = a2 * (1.0f / 128.0f);
  psd_s[t] = psd;
  float fr = (t < 64) ? (float)t * (1.0f / 128.0f) : ((float)t - 128.0f) * (1.0f / 128.0f);
  __syncthreads();

  float psum = rsum128(psd, red2);
  float mfn  = rsum128(fr * psd, red2);
  float p2   = rsum128(psd * psd, red2);
  float maxp = rmax128(psd, red2);
  float cand = (psd == maxp) ? (float)t : 1e9f;       // first-index argmax
  float kmin = rmin128(cand, red2);
  int   k0   = (int)kmin;
  float fmaxfreq = (k0 < 64) ? (float)k0 * (1.0f / 128.0f)
                             : ((float)k0 - 128.0f) * (1.0f / 128.0f);
  float max_amp = sqrtf(maxp * 128.0f);

  // stable-rank median: element at sorted position 64
  int cnt = 0;
  float pj = psd;
  for (int i = 0; i < 128; ++i){
    float pi = psd_s[i];
    cnt += (pi < pj || (pi == pj && i < t)) ? 1 : 0;
  }
  float* o = Xf + pp * 40;
  if (cnt == 64) o[13] = fr;     // median_freq
  if (t == 0){
    o[0]  = mx;  o[1]  = mn;  o[2]  = sd;   o[3]  = rms; o[4]  = mean;
    o[5]  = mx - mn;  o[6] = var;  o[7] = ent; o[8] = std_asin; o[9] = std_atan;
    o[10] = kurt; o[11] = skew;
    o[12] = mfn / psum;
    o[14] = psum;                  // band_power
    o[15] = 1.0f;                  // occ: all freqs < fs/2 exactly
    o[16] = sqrtf(p2 / psum);      // pbw
    o[17] = maxp;
    o[18] = max_amp;
    o[19] = fmaxfreq;
  }
}

// ---------- K2: cumsum feature + per-sample normalization (in-place on Xf) ----------
__global__ __launch_bounds__(256) void cumnorm_kernel(float* __restrict__ Xf){
  const int b = blockIdx.x, t = threadIdx.x;
  __shared__ float arr[128 * 40];
  __shared__ float red4[4];
  float* base = Xf + b * 5120;
  for (int idx = t; idx < 128 * 20; idx += 256){
    int p = idx / 20, c = idx - p * 20;
    arr[p * 40 + c] = base[p * 40 + c];
  }
  __syncthreads();
  if (t < 20){
    float acc = 0.f;
    for (int p = 0; p < 128; ++p){
      acc += arr[p * 40 + t];
      arr[p * 40 + 20 + t] = acc / sqrtf(fmaxf(fabsf(acc), 1e-12f));
    }
  }
  __syncthreads();
  float pa = 0.f;
  for (int idx = t; idx < 5120; idx += 256){ float v = arr[idx]; pa = fmaf(v, v, pa); }
  float nrm = sqrtf(rsum256(pa, red4));
  for (int idx = t; idx < 5120; idx += 256) base[idx] = arr[idx] / nrm;
}

// ---------- K3: A_t = tanh(Xf@w1+b1)@w2+b2  (128x128 per sample) ----------
__global__ __launch_bounds__(256) void adjt_kernel(const float* __restrict__ Xf,
    const float* __restrict__ w1, const float* __restrict__ b1,
    const float* __restrict__ w2, const float* __restrict__ b2,
    float* __restrict__ At){
  const int b = blockIdx.x, t = threadIdx.x;
  __shared__ float xf[5120];
  __shared__ float T[128 * 64];
  const float* src = Xf + b * 5120;
  for (int idx = t; idx < 5120; idx += 256) xf[idx] = src[idx];
  __syncthreads();
  for (int idx = t; idx < 128 * 64; idx += 256){
    int i = idx >> 6, k = idx & 63;
    float acc = b1[k];
    #pragma unroll 8
    for (int c = 0; c < 40; ++c) acc = fmaf(xf[i * 40 + c], w1[c * 64 + k], acc);
    T[idx] = tanhf(acc);
  }
  __syncthreads();
  float* dst = At + b * 16384;
  for (int idx = t; idx < 16384; idx += 256){
    int i = idx >> 7, j = idx & 127;
    float acc = b2[j];
    #pragma unroll 8
    for (int k = 0; k < 64; ++k) acc = fmaf(T[i * 64 + k], w2[k * 128 + j], acc);
    dst[idx] = acc;
  }
}

// ---------- K4: A_s = tanh(Xt@w1+b1)@w2+b2  (40x40 per sample) ----------
__global__ __launch_bounds__(256) void adjs_kernel(const float* __restrict__ Xf,
    const float* __restrict__ w1, const float* __restrict__ b1,
    const float* __restrict__ w2, const float* __restrict__ b2,
    float* __restrict__ As){
  const int b = blockIdx.x, t = threadIdx.x;
  __shared__ float xf[5120];
  __shared__ float T2[40 * 64];
  const float* src = Xf + b * 5120;
  for (int idx = t; idx < 5120; idx += 256) xf[idx] = src[idx];
  __syncthreads();
  for (int idx = t; idx < 40 * 64; idx += 256){
    int i = idx >> 6, k = idx & 63;
    float acc = b1[k];
    for (int p = 0; p < 128; ++p) acc = fmaf(xf[p * 40 + i], w1[p * 64 + k], acc);
    T2[idx] = tanhf(acc);
  }
  __syncthreads();
  float* dst = As + b * 1600;
  for (int idx = t; idx < 1600; idx += 256){
    int i = idx / 40, j = idx - i * 40;
    float acc = b2[j];
    #pragma unroll 8
    for (int k = 0; k < 64; ++k) acc = fmaf(T2[i * 64 + k], w2[k * 40 + j], acc);
    dst[idx] = acc;
  }
}

// ---------- K5: H_s = leaky(A_s@Xt@sgnn_w + b) -> H rows 0..39 ----------
__global__ __launch_bounds__(256) void hs_kernel(const float* __restrict__ Xf,
    const float* __restrict__ As_g, const float* __restrict__ w, const float* __restrict__ bias,
    float* __restrict__ H){
  const int b = blockIdx.x, t = threadIdx.x;
  __shared__ float xf[128 * 41];
  __shared__ float As[1600];
  __shared__ float M[40 * 128];
  const float* src = Xf + b * 5120;
  for (int idx = t; idx < 5120; idx += 256){ int p = idx / 40, c = idx - p * 40; xf[p * 41 + c] = src[idx]; }
  for (int idx = t; idx < 1600; idx += 256) As[idx] = As_g[b * 1600 + idx];
  __syncthreads();
  for (int idx = t; idx < 5120; idx += 256){
    int i = idx >> 7, p = idx & 127;
    float acc = 0.f;
    #pragma unroll 8
    for (int m = 0; m < 40; ++m) acc = fmaf(As[i * 40 + m], xf[p * 41 + m], acc);
    M[i * 128 + p] = acc;
  }
  __syncthreads();
  float* dst = H + b * (N * HG);
  for (int idx = t; idx < 5120; idx += 256){
    int i = idx >> 7, j = idx & 127;
    float acc = bias[j];
    for (int p = 0; p < 128; ++p) acc = fmaf(M[i * 128 + p], w[p * 128 + j], acc);
    dst[i * 128 + j] = (acc >= 0.f) ? acc : 0.01f * acc;
  }
}

// ---------- K6: H_t = leaky(A_t@Xf@tgnn_w + b) -> H rows 40..167 ----------
__global__ __launch_bounds__(256) void ht_kernel(const float* __restrict__ Xf,
    const float* __restrict__ At_g, const float* __restrict__ w, const float* __restrict__ bias,
    float* __restrict__ H){
  const int b = blockIdx.x, t = threadIdx.x;
  __shared__ float xf[128 * 41];
  __shared__ float M2[128 * 40];
  const float* src = Xf + b * 5120;
  for (int idx = t; idx < 5120; idx += 256){ int p = idx / 40, c = idx - p * 40; xf[p * 41 + c] = src[idx]; }
  __syncthreads();
  const float* At = At_g + b * 16384;
  for (int idx = t; idx < 5120; idx += 256){
    int i = idx / 40, c = idx - i * 40;
    float acc = 0.f;
    for (int m = 0; m < 128; ++m) acc = fmaf(At[i * 128 + m], xf[m * 41 + c], acc);
    M2[i * 40 + c] = acc;
  }
  __syncthreads();
  float* dst = H + b * (N * HG) + 40 * 128;
  for (int idx = t; idx < 16384; idx += 256){
    int i = idx >> 7, j = idx & 127;
    float acc = bias[j];
    #pragma unroll 8
    for (int c = 0; c < 40; ++c) acc = fmaf(M2[i * 40 + c], w[c * 128 + j], acc);
    dst[i * 128 + j] = (acc >= 0.f) ? acc : 0.01f * acc;
  }
}

// ---------- init out with fc_b ----------
__global__ void initout_kernel(float* __restrict__ out, const float* __restrict__ fcb){
  int i = blockIdx.x * 256 + threadIdx.x;
  if (i < BSZ) out[i] = fcb[0];
}

// ---------- K7: QKV for one batch chunk ----------
__global__ __launch_bounds__(128) void qkv_kernel(const float* __restrict__ Hg,
    const float* __restrict__ qw, const float* __restrict__ qb,
    const float* __restrict__ kw, const float* __restrict__ kb,
    const float* __restrict__ vw, const float* __restrict__ vb,
    float* __restrict__ QKV, int b0){
  const int bl = blockIdx.x, h = blockIdx.y, z = blockIdx.z;
  const int b = b0 + bl;
  const float* W; const float* bias;
  if (z == 0){ W = qw; bias = qb; }
  else if (z == 1){ W = kw; bias = kb; }
  else { W = vw; bias = vb; }
  W += h * (HG * HG); bias += h * HG;
  float* Out = QKV + z * CHUNK_QKV + (bl * NH + h) * (N * HG);
  const float* Hb = Hg + b * (N * HG);
  const int e = threadIdx.x;
  for (int g = 0; g < 21; ++g){
    const int n0 = g * 8;
    float acc[8];
    #pragma unroll
    for (int r = 0; r < 8; ++r) acc[r] = 0.f;
    for (int d = 0; d < 128; d += 4){
      float4 hv[8];
      #pragma unroll
      for (int r = 0; r < 8; ++r) hv[r] = *reinterpret_cast<const float4*>(&Hb[(n0 + r) * 128 + d]);
      #pragma unroll
      for (int q = 0; q < 4; ++q){
        float wv = W[(d + q) * 128 + e];
        #pragma unroll
        for (int r = 0; r < 8; ++r) acc[r] = fmaf((&hv[r].x)[q], wv, acc[r]);
      }
    }
    float bv = bias[e];
    #pragma unroll
    for (int r = 0; r < 8; ++r) Out[(n0 + r) * 128 + e] = acc[r] + bv;
  }
}

// ---------- K8: fused scores+softmax+O+fc for one chunk ----------
// block: (bh = bl*4+h, tile of 42 Q-rows); accumulates into out[b] via atomicAdd
__global__ __launch_bounds__(256) void attn_kernel(const float* __restrict__ QKV,
    const float* __restrict__ fcw, float* __restrict__ out, int b0){
  const int bh = blockIdx.x;
  const int tile = blockIdx.y;
  const int h = bh & 3;
  const int b = b0 + (bh >> 2);
  const float* Q  = QKV + bh * (N * HG);
  const float* Kp = QKV + CHUNK_QKV + bh * (N * HG);
  const float* Vp = QKV + 2 * CHUNK_QKV + bh * (N * HG);
  __shared__ float q[42 * 129];
  __shared__ float kt[21 * 129];
  __shared__ float sc[42 * 170];
  __shared__ float rowred[42 * 8];
  __shared__ float red4[4];
  const int t = threadIdx.x;
  const int n0 = tile * 42;

  for (int idx = t; idx < 42 * 128; idx += 256){
    int n = idx >> 7, d = idx & 127;
    q[n * 129 + d] = Q[(n0 + n) * 128 + d];
  }
  const float inv = 0.08838834764831845f;   // 1/sqrt(128)
  for (int mt = 0; mt < 8; ++mt){
    __syncthreads();
    for (int idx = t; idx < 21 * 128; idx += 256){
      int m = idx >> 7, d = idx & 127;
      kt[m * 129 + d] = Kp[(mt * 21 + m) * 128 + d];
    }
    __syncthreads();
    for (int idx = t; idx < 42 * 21; idx += 256){
      int nn = idx / 21, mm = idx - nn * 21;
      float acc = 0.f;
      #pragma unroll 8
      for (int d = 0; d < 128; ++d) acc = fmaf(q[nn * 129 + d], kt[mm * 129 + d], acc);
      sc[nn * 170 + mt * 21 + mm] = acc * inv;
    }
  }
  __syncthreads();
  { // softmax over 168 per row; 6 threads per row
    const int r = t / 6, j = t - (t / 6) * 6;
    if (r < 42){
      float mxv = -1e30f;
      for (int m = j * 28; m < j * 28 + 28; ++m) mxv = fmaxf(mxv, sc[r * 170 + m]);
      rowred[r * 8 + j] = mxv;
    }
    __syncthreads();
    if (t < 42){
      float mxv = rowred[t * 8];
      for (int j2 = 1; j2 < 6; ++j2) mxv = fmaxf(mxv, rowred[t * 8 + j2]);
      rowred[t * 8 + 6] = mxv;
    }
    __syncthreads();
    if (r < 42){
      float mxv = rowred[r * 8 + 6];
      float sm = 0.f;
      for (int m = j * 28; m < j * 28 + 28; ++m) sm += expf(sc[r * 170 + m] - mxv);
      rowred[r * 8 + j] = sm;
    }
    __syncthreads();
    if (t < 42){
      float sm = 0.f;
      for (int j2 = 0; j2 < 6; ++j2) sm += rowred[t * 8 + j2];
      rowred[t * 8 + 7] = sm;
    }
    __syncthreads();
    for (int idx = t; idx < 42 * 168; idx += 256){
      int r2 = idx / 168, m = idx - r2 * 168;
      sc[r2 * 170 + m] = expf(sc[r2 * 170 + m] - rowred[r2 * 8 + 6]) / rowred[r2 * 8 + 7];
    }
  }
  __syncthreads();
  // O = attn @ V fused with fc contraction
  const int e = t & 127, half = t >> 7;
  float tp = 0.f;
  for (int gr = 0; gr < 7; ++gr){
    const int r0 = half * 21 + gr * 3;
    float a0 = 0.f, a1 = 0.f, a2v = 0.f;
    for (int m = 0; m < 168; ++m){
      float v = Vp[m * 128 + e];
      a0  = fmaf(sc[(r0 + 0) * 170 + m], v, a0);
      a1  = fmaf(sc[(r0 + 1) * 170 + m], v, a1);
      a2v = fmaf(sc[(r0 + 2) * 170 + m], v, a2v);
    }
    const int nb = n0 + r0;
    tp = fmaf(a0,  fcw[(nb + 0) * 512 + h * 128 + e], tp);
    tp = fmaf(a1,  fcw[(nb + 1) * 512 + h * 128 + e], tp);
    tp = fmaf(a2v, fcw[(nb + 2) * 512 + h * 128 + e], tp);
  }
  float tot = rsum256(tp, red4);
  if (t == 0) atomicAdd(&out[b], tot);
}

} // anonymous namespace

extern "C" void kernel_launch(void* const* d_in, const int* in_sizes, int n_in,
                              void* d_out, int out_size, void* d_ws, size_t ws_size,
                              hipStream_t stream) {
  (void)in_sizes; (void)n_in; (void)out_size;
  const float* X      = (const float*)d_in[0];
  const float* spa_w1 = (const float*)d_in[1];
  const float* spa_b1 = (const float*)d_in[2];
  const float* spa_w2 = (const float*)d_in[3];
  const float* spa_b2 = (const float*)d_in[4];
  const float* tem_w1 = (const float*)d_in[5];
  const float* tem_b1 = (const float*)d_in[6];
  const float* tem_w2 = (const float*)d_in[7];
  const float* tem_b2 = (const float*)d_in[8];
  const float* sgnn_w = (const float*)d_in[9];
  const float* sgnn_b = (const float*)d_in[10];
  const float* tgnn_w = (const float*)d_in[11];
  const float* tgnn_b = (const float*)d_in[12];
  const float* q_w    = (const float*)d_in[13];
  const float* q_b    = (const float*)d_in[14];
  const float* k_w    = (const float*)d_in[15];
  const float* k_b    = (const float*)d_in[16];
  const float* v_w    = (const float*)d_in[17];
  const float* v_b    = (const float*)d_in[18];
  const float* fc_w   = (const float*)d_in[19];
  const float* fc_b   = (const float*)d_in[20];
  float* out = (float*)d_out;
  float* ws  = (float*)d_ws;

  // workspace layout (floats):
  //   H:  [0, 1024*168*128)                            = 22,020,096
  //   R:  phase1: Xf(5,242,880) | As(1,638,400) | At(16,777,216)
  //       phase2 (reuse): Q|K|V chunk (3 * 5,505,024)
  // total = 45,678,592 floats = 182,714,368 bytes
  if (ws_size < (size_t)45678592 * 4) return;   // insufficient scratch -> clean fail

  float* Hbuf = ws;
  float* R    = ws + (size_t)BSZ * N * HG;
  float* Xf   = R;
  float* As   = R + (size_t)BSZ * 5120;
  float* At   = As + (size_t)BSZ * 1600;
  float* QKV  = R;   // phase-2 reuse (Xf/As/At dead by then)

  feat_kernel<<<BSZ * P, 128, 0, stream>>>(X, Xf);
  cumnorm_kernel<<<BSZ, 256, 0, stream>>>(Xf);
  adjt_kernel<<<BSZ, 256, 0, stream>>>(Xf, tem_w1, tem_b1, tem_w2, tem_b2, At);
  adjs_kernel<<<BSZ, 256, 0, stream>>>(Xf, spa_w1, spa_b1, spa_w2, spa_b2, As);
  hs_kernel<<<BSZ, 256, 0, stream>>>(Xf, As, sgnn_w, sgnn_b, Hbuf);
  ht_kernel<<<BSZ, 256, 0, stream>>>(Xf, At, tgnn_w, tgnn_b, Hbuf);
  initout_kernel<<<4, 256, 0, stream>>>(out, fc_b);
  for (int c = 0; c < BSZ / CB; ++c){
    qkv_kernel<<<dim3(CB, NH, 3), 128, 0, stream>>>(Hbuf, q_w, q_b, k_w, k_b, v_w, v_b, QKV, c * CB);
    attn_kernel<<<dim3(CB * NH, 4), 256, 0, stream>>>(QKV, fc_w, out, c * CB);
  }
}

// Round 2
// 2450.285 us; speedup vs baseline: 3.3056x; 3.3056x over previous
//
#include <hip/hip_runtime.h>
#include <math.h>

namespace {

constexpr int BSZ  = 1024;
constexpr int P    = 128;
constexpr int HG   = 128;
constexpr int NH   = 4;
constexpr int N    = 168;     // P + IND
constexpr int NPAD = 176;     // padded token count (11 tiles of 16)

typedef short bf16x8 __attribute__((ext_vector_type(8)));
typedef float f32x4  __attribute__((ext_vector_type(4)));

__device__ __forceinline__ unsigned short f2bf(float x){
  union { float f; unsigned u; } v; v.f = x;
  unsigned r = (v.u + 0x7FFF + ((v.u >> 16) & 1)) >> 16;
  return (unsigned short)r;
}
__device__ __forceinline__ float bf2f(unsigned short b){
  union { unsigned u; float f; } v; v.u = ((unsigned)b) << 16;
  return v.f;
}

// ---------- block reductions ----------
__device__ __forceinline__ float rsum128(float v, volatile float* red2){
  #pragma unroll
  for (int o = 32; o > 0; o >>= 1) v += __shfl_down(v, o, 64);
  __syncthreads();
  if ((threadIdx.x & 63) == 0) red2[threadIdx.x >> 6] = v;
  __syncthreads();
  return red2[0] + red2[1];
}
__device__ __forceinline__ float rmax128(float v, volatile float* red2){
  #pragma unroll
  for (int o = 32; o > 0; o >>= 1) v = fmaxf(v, __shfl_down(v, o, 64));
  __syncthreads();
  if ((threadIdx.x & 63) == 0) red2[threadIdx.x >> 6] = v;
  __syncthreads();
  return fmaxf(red2[0], red2[1]);
}
__device__ __forceinline__ float rmin128(float v, volatile float* red2){
  #pragma unroll
  for (int o = 32; o > 0; o >>= 1) v = fminf(v, __shfl_down(v, o, 64));
  __syncthreads();
  if ((threadIdx.x & 63) == 0) red2[threadIdx.x >> 6] = v;
  __syncthreads();
  return fminf(red2[0], red2[1]);
}
__device__ __forceinline__ float rsum256(float v, volatile float* red4){
  #pragma unroll
  for (int o = 32; o > 0; o >>= 1) v += __shfl_down(v, o, 64);
  __syncthreads();
  if ((threadIdx.x & 63) == 0) red4[threadIdx.x >> 6] = v;
  __syncthreads();
  return red4[0] + red4[1] + red4[2] + red4[3];
}

// ---------- K1: per-patch features (temporal + DFT) ----------
__global__ __launch_bounds__(128) void feat_kernel(const float* __restrict__ X,
                                                   float* __restrict__ Xf){
  const int pp = blockIdx.x;       // b*128 + p
  const int t  = threadIdx.x;      // 0..127
  __shared__ float  sv[128];
  __shared__ float2 tw[128];
  __shared__ float  psd_s[128];
  __shared__ float  red2[2];

  float x = X[pp * 128 + t];
  sv[t] = x;
  if (t <= 64){
    double ang = 6.283185307179586476925286766559 * (double)t / 128.0;
    tw[t] = make_float2(cosf((float)ang), -sinf((float)ang));
  }
  __syncthreads();
  if (t >= 65){
    float2 w = tw[128 - t];        // exact conjugate mirror -> bitwise-symmetric psd
    tw[t] = make_float2(w.x, -w.y);
  }

  float mx    = rmax128(x, red2);
  float mn    = rmin128(x, red2);
  float mean  = rsum128(x, red2) * (1.0f / 128.0f);
  float sumsq = rsum128(x * x, red2);
  float cen = x - mean;
  float c2  = cen * cen;
  float m2  = rsum128(c2, red2);
  float m3  = rsum128(c2 * cen, red2);
  float m4  = rsum128(c2 * c2, red2);
  float var = m2 * (1.0f / 127.0f);
  float sd  = sqrtf(var);
  float rms = sqrtf(sumsq * (1.0f / 128.0f));
  float ex  = expf(x - mx);
  float Z   = rsum128(ex, red2);
  float SxE = rsum128(ex * x, red2);
  float ent = (mx + logf(Z)) - SxE / Z;
  const float lo = (float)(-1.0 + 1e-7), hi = (float)(1.0 - 1e-7);
  float aa = asinf(fminf(fmaxf(x, lo), hi));
  float amean = rsum128(aa, red2) * (1.0f / 128.0f);
  float ad = aa - amean;
  float std_asin = sqrtf(rsum128(ad * ad, red2) * (1.0f / 127.0f));
  float bb = atanf(x);
  float bmean = rsum128(bb, red2) * (1.0f / 128.0f);
  float bd = bb - bmean;
  float std_atan = sqrtf(rsum128(bd * bd, red2) * (1.0f / 127.0f));
  float kurt = (m4 * (1.0f / 128.0f)) / (sd * sd * sd * sd) - 3.0f;
  float skew = (m3 * (1.0f / 128.0f)) / (sd * sd * sd);

  float re = 0.f, im = 0.f;
  int idx = 0;
  for (int tt = 0; tt < 128; ++tt){
    float s0 = sv[tt];
    float2 w = tw[idx];
    re = fmaf(s0, w.x, re);
    im = fmaf(s0, w.y, im);
    idx = (idx + t) & 127;
  }
  float a2  = re * re + im * im;
  float psd = a2 * (1.0f / 128.0f);
  psd_s[t] = psd;
  float fr = (t < 64) ? (float)t * (1.0f / 128.0f) : ((float)t - 128.0f) * (1.0f / 128.0f);
  __syncthreads();

  float psum = rsum128(psd, red2);
  float mfn  = rsum128(fr * psd, red2);
  float p2   = rsum128(psd * psd, red2);
  float maxp = rmax128(psd, red2);
  float cand = (psd == maxp) ? (float)t : 1e9f;
  float kmin = rmin128(cand, red2);
  int   k0   = (int)kmin;
  float fmaxfreq = (k0 < 64) ? (float)k0 * (1.0f / 128.0f)
                             : ((float)k0 - 128.0f) * (1.0f / 128.0f);
  float max_amp = sqrtf(maxp * 128.0f);

  int cnt = 0;
  float pj = psd;
  for (int i = 0; i < 128; ++i){
    float pi = psd_s[i];
    cnt += (pi < pj || (pi == pj && i < t)) ? 1 : 0;
  }
  float* o = Xf + pp * 40;
  if (cnt == 64) o[13] = fr;
  if (t == 0){
    o[0]  = mx;  o[1]  = mn;  o[2]  = sd;   o[3]  = rms; o[4]  = mean;
    o[5]  = mx - mn;  o[6] = var;  o[7] = ent; o[8] = std_asin; o[9] = std_atan;
    o[10] = kurt; o[11] = skew;
    o[12] = mfn / psum;
    o[14] = psum;
    o[15] = 1.0f;
    o[16] = sqrtf(p2 / psum);
    o[17] = maxp;
    o[18] = max_amp;
    o[19] = fmaxfreq;
  }
}

// ---------- K2: cumsum feature + per-sample normalization ----------
__global__ __launch_bounds__(256) void cumnorm_kernel(float* __restrict__ Xf){
  const int b = blockIdx.x, t = threadIdx.x;
  __shared__ float arr[128 * 40];
  __shared__ float red4[4];
  float* base = Xf + b * 5120;
  for (int idx = t; idx < 128 * 20; idx += 256){
    int p = idx / 20, c = idx - p * 20;
    arr[p * 40 + c] = base[p * 40 + c];
  }
  __syncthreads();
  if (t < 20){
    float acc = 0.f;
    for (int p = 0; p < 128; ++p){
      acc += arr[p * 40 + t];
      arr[p * 40 + 20 + t] = acc / sqrtf(fmaxf(fabsf(acc), 1e-12f));
    }
  }
  __syncthreads();
  float pa = 0.f;
  for (int idx = t; idx < 5120; idx += 256){ float v = arr[idx]; pa = fmaf(v, v, pa); }
  float nrm = sqrtf(rsum256(pa, red4));
  for (int idx = t; idx < 5120; idx += 256) base[idx] = arr[idx] / nrm;
}

// ---------- K3: A_t ----------
__global__ __launch_bounds__(256) void adjt_kernel(const float* __restrict__ Xf,
    const float* __restrict__ w1, const float* __restrict__ b1,
    const float* __restrict__ w2, const float* __restrict__ b2,
    float* __restrict__ At){
  const int b = blockIdx.x, t = threadIdx.x;
  __shared__ float xf[5120];
  __shared__ float T[128 * 64];
  const float* src = Xf + b * 5120;
  for (int idx = t; idx < 5120; idx += 256) xf[idx] = src[idx];
  __syncthreads();
  for (int idx = t; idx < 128 * 64; idx += 256){
    int i = idx >> 6, k = idx & 63;
    float acc = b1[k];
    #pragma unroll 8
    for (int c = 0; c < 40; ++c) acc = fmaf(xf[i * 40 + c], w1[c * 64 + k], acc);
    T[idx] = tanhf(acc);
  }
  __syncthreads();
  float* dst = At + b * 16384;
  for (int idx = t; idx < 16384; idx += 256){
    int i = idx >> 7, j = idx & 127;
    float acc = b2[j];
    #pragma unroll 8
    for (int k = 0; k < 64; ++k) acc = fmaf(T[i * 64 + k], w2[k * 128 + j], acc);
    dst[idx] = acc;
  }
}

// ---------- K4: A_s ----------
__global__ __launch_bounds__(256) void adjs_kernel(const float* __restrict__ Xf,
    const float* __restrict__ w1, const float* __restrict__ b1,
    const float* __restrict__ w2, const float* __restrict__ b2,
    float* __restrict__ As){
  const int b = blockIdx.x, t = threadIdx.x;
  __shared__ float xf[5120];
  __shared__ float T2[40 * 64];
  const float* src = Xf + b * 5120;
  for (int idx = t; idx < 5120; idx += 256) xf[idx] = src[idx];
  __syncthreads();
  for (int idx = t; idx < 40 * 64; idx += 256){
    int i = idx >> 6, k = idx & 63;
    float acc = b1[k];
    for (int p = 0; p < 128; ++p) acc = fmaf(xf[p * 40 + i], w1[p * 64 + k], acc);
    T2[idx] = tanhf(acc);
  }
  __syncthreads();
  float* dst = As + b * 1600;
  for (int idx = t; idx < 1600; idx += 256){
    int i = idx / 40, j = idx - i * 40;
    float acc = b2[j];
    #pragma unroll 8
    for (int k = 0; k < 64; ++k) acc = fmaf(T2[i * 64 + k], w2[k * 40 + j], acc);
    dst[idx] = acc;
  }
}

// ---------- K5: H_s ----------
__global__ __launch_bounds__(256) void hs_kernel(const float* __restrict__ Xf,
    const float* __restrict__ As_g, const float* __restrict__ w, const float* __restrict__ bias,
    float* __restrict__ H){
  const int b = blockIdx.x, t = threadIdx.x;
  __shared__ float xf[128 * 41];
  __shared__ float As[1600];
  __shared__ float M[40 * 128];
  const float* src = Xf + b * 5120;
  for (int idx = t; idx < 5120; idx += 256){ int p = idx / 40, c = idx - p * 40; xf[p * 41 + c] = src[idx]; }
  for (int idx = t; idx < 1600; idx += 256) As[idx] = As_g[b * 1600 + idx];
  __syncthreads();
  for (int idx = t; idx < 5120; idx += 256){
    int i = idx >> 7, p = idx & 127;
    float acc = 0.f;
    #pragma unroll 8
    for (int m = 0; m < 40; ++m) acc = fmaf(As[i * 40 + m], xf[p * 41 + m], acc);
    M[i * 128 + p] = acc;
  }
  __syncthreads();
  float* dst = H + (size_t)b * (N * HG);
  for (int idx = t; idx < 5120; idx += 256){
    int i = idx >> 7, j = idx & 127;
    float acc = bias[j];
    for (int p = 0; p < 128; ++p) acc = fmaf(M[i * 128 + p], w[p * 128 + j], acc);
    dst[i * 128 + j] = (acc >= 0.f) ? acc : 0.01f * acc;
  }
}

// ---------- K6: H_t ----------
__global__ __launch_bounds__(256) void ht_kernel(const float* __restrict__ Xf,
    const float* __restrict__ At_g, const float* __restrict__ w, const float* __restrict__ bias,
    float* __restrict__ H){
  const int b = blockIdx.x, t = threadIdx.x;
  __shared__ float xf[128 * 41];
  __shared__ float M2[128 * 40];
  const float* src = Xf + b * 5120;
  for (int idx = t; idx < 5120; idx += 256){ int p = idx / 40, c = idx - p * 40; xf[p * 41 + c] = src[idx]; }
  __syncthreads();
  const float* At = At_g + (size_t)b * 16384;
  for (int idx = t; idx < 5120; idx += 256){
    int i = idx / 40, c = idx - i * 40;
    float acc = 0.f;
    for (int m = 0; m < 128; ++m) acc = fmaf(At[i * 128 + m], xf[m * 41 + c], acc);
    M2[i * 40 + c] = acc;
  }
  __syncthreads();
  float* dst = H + (size_t)b * (N * HG) + 40 * 128;
  for (int idx = t; idx < 16384; idx += 256){
    int i = idx >> 7, j = idx & 127;
    float acc = bias[j];
    #pragma unroll 8
    for (int c = 0; c < 40; ++c) acc = fmaf(M2[i * 40 + c], w[c * 128 + j], acc);
    dst[i * 128 + j] = (acc >= 0.f) ? acc : 0.01f * acc;
  }
}

__global__ void initout_kernel(float* __restrict__ out, const float* __restrict__ fcb){
  int i = blockIdx.x * 256 + threadIdx.x;
  if (i < BSZ) out[i] = fcb[0];
}

// ---------- prep: per-head M^T = (Wq Wk^T)^T, Wv^T, c1/c2/c3 (bf16 weights) ----------
__global__ __launch_bounds__(256) void prep_kernel(
    const float* __restrict__ qw, const float* __restrict__ qb,
    const float* __restrict__ kw, const float* __restrict__ kb,
    const float* __restrict__ vw,
    short* __restrict__ MT, short* __restrict__ WvT,
    float* __restrict__ c1, float* __restrict__ c2, float* __restrict__ c3){
  const int h = blockIdx.x, t = threadIdx.x;
  const float* Q = qw + h * 16384;
  const float* K = kw + h * 16384;
  const float* V = vw + h * 16384;
  for (int idx = t; idx < 16384; idx += 256){
    int j = idx >> 7, d = idx & 127;
    float acc = 0.f;
    for (int e = 0; e < 128; ++e) acc = fmaf(Q[d * 128 + e], K[j * 128 + e], acc);
    MT[h * 16384 + j * 128 + d] = (short)f2bf(acc);     // MT[j][d] = M[d][j]
  }
  for (int idx = t; idx < 16384; idx += 256){
    int e = idx >> 7, d = idx & 127;
    WvT[h * 16384 + idx] = (short)f2bf(V[d * 128 + e]); // WvT[e][d] = Wv[d][e]
  }
  if (t < 128){
    float a = 0.f, bsum = 0.f;
    for (int e = 0; e < 128; ++e){
      a    = fmaf(Q[t * 128 + e], kb[h * 128 + e], a);
      bsum = fmaf(K[t * 128 + e], qb[h * 128 + e], bsum);
    }
    c1[h * 128 + t] = a;
    c2[h * 128 + t] = bsum;
  }
  if (t == 128){
    float a = 0.f;
    for (int e = 0; e < 128; ++e) a = fmaf(qb[h * 128 + e], kb[h * 128 + e], a);
    c3[h] = a;
  }
}

// ---------- cast H -> bf16 with zero-padded rows 168..175 ----------
__global__ __launch_bounds__(256) void cast_kernel(const float* __restrict__ H,
                                                   short* __restrict__ Hbf){
  const int b = blockIdx.x;
  for (int idx = threadIdx.x; idx < NPAD * 128; idx += 256){
    int n = idx >> 7, d = idx & 127;
    float v = (n < N) ? H[((size_t)b * N + n) * 128 + d] : 0.f;
    Hbf[(size_t)b * NPAD * 128 + idx] = (short)f2bf(v);
  }
}

// ---------- attention mega-kernel ----------
// grid (b, h, z). z=0: rows 0..95 (6 tiles), z=1: rows 96..175 (5 tiles).
// scores = (H M H^T + u1_n + u2_m + c3)/sqrt(128); P = softmax; O = (P H) Wv + vb;
// out[b] += sum_{n<168,e} O[n][e] * fcw[n*512 + h*128 + e]   (O never materialized)
__global__ __launch_bounds__(256) void attn_mega(
    const short* __restrict__ Hbf, const short* __restrict__ MT,
    const short* __restrict__ WvT, const float* __restrict__ c1g,
    const float* __restrict__ c2g, const float* __restrict__ c3g,
    const float* __restrict__ vb, const float* __restrict__ fcw,
    float* __restrict__ out){
  const int b = blockIdx.x, h = blockIdx.y, z = blockIdx.z;
  const int rowbase = z * 96;
  const int rows = z ? 80 : 96;
  const int NT = z ? 5 : 6;
  const int t = threadIdx.x;
  const int w = t >> 6, l = t & 63, quad = l >> 4, l15 = l & 15;

  __shared__ __align__(16) short Tsh[96 * 128];   // T then U (XOR-swizzled rows)
  __shared__ __align__(16) short Ssh[96 * 200];   // S then P (bf16, stride 200)
  __shared__ float u1s[96];
  __shared__ float u2s[176];
  __shared__ float red4[4];

  const short* Hb = Hbf + (size_t)b * NPAD * 128;
  const short* MTh = MT + h * 16384;
  const short* WvTh = WvT + h * 16384;
  const float c3v = c3g[h];
  const float inv = 0.08838834764831845f;   // 1/sqrt(128)

  // stage c1,c2 into (dead) T region
  float* stage = (float*)Tsh;
  if (t < 128) stage[t] = c1g[h * 128 + t];
  else stage[t] = c2g[h * 128 + (t - 128)];
  __syncthreads();

  // u1 (own rows), u2 (all 176 rows); H pad rows are zero -> u=0 naturally
  if (t < 176){
    float acc = 0.f;
    const bf16x8* rp = (const bf16x8*)(Hb + (size_t)t * 128);
    for (int kk = 0; kk < 16; ++kk){
      bf16x8 v = rp[kk];
      #pragma unroll
      for (int j = 0; j < 8; ++j)
        acc = fmaf(bf2f((unsigned short)v[j]), stage[128 + kk * 8 + j], acc);
    }
    u2s[t] = acc;
  }
  if (t < rows){
    float acc = 0.f;
    const bf16x8* rp = (const bf16x8*)(Hb + (size_t)(rowbase + t) * 128);
    for (int kk = 0; kk < 16; ++kk){
      bf16x8 v = rp[kk];
      #pragma unroll
      for (int j = 0; j < 8; ++j)
        acc = fmaf(bf2f((unsigned short)v[j]), stage[kk * 8 + j], acc);
    }
    u1s[t] = acc;
  }
  __syncthreads();

  // ---- Phase A: T = H_rows @ M   (write bf16, swizzled) ----
  for (int jt = 0; jt < 2; ++jt){
    const int j0 = (w * 2 + jt) * 16;
    bf16x8 B[4];
    #pragma unroll
    for (int kk = 0; kk < 4; ++kk)
      B[kk] = *(const bf16x8*)(MTh + (j0 + l15) * 128 + kk * 32 + quad * 8);
    for (int nt = 0; nt < NT; ++nt){
      f32x4 acc = {0.f, 0.f, 0.f, 0.f};
      #pragma unroll
      for (int kk = 0; kk < 4; ++kk){
        bf16x8 A = *(const bf16x8*)(Hb + (size_t)(rowbase + nt * 16 + l15) * 128 + kk * 32 + quad * 8);
        acc = __builtin_amdgcn_mfma_f32_16x16x32_bf16(A, B[kk], acc, 0, 0, 0);
      }
      const int jcol = j0 + l15, ch = jcol >> 3;
      #pragma unroll
      for (int r = 0; r < 4; ++r){
        int row = nt * 16 + quad * 4 + r;
        Tsh[row * 128 + ((ch ^ (row & 15)) << 3) + (jcol & 7)] = (short)f2bf(acc[r]);
      }
    }
  }
  __syncthreads();

  // ---- Phase B: S = T @ H^T (+rank-1 terms), bf16 into Ssh ----
  for (int mi = 0; mi < 3; ++mi){
    const int mt = w + mi * 4;
    if (mt >= 11) break;
    const int m0 = mt * 16;
    bf16x8 B[4];
    #pragma unroll
    for (int kk = 0; kk < 4; ++kk)
      B[kk] = *(const bf16x8*)(Hb + (size_t)(m0 + l15) * 128 + kk * 32 + quad * 8);
    const int m = m0 + l15;
    const float u2v = u2s[m];
    for (int nt = 0; nt < NT; ++nt){
      f32x4 acc = {0.f, 0.f, 0.f, 0.f};
      #pragma unroll
      for (int kk = 0; kk < 4; ++kk){
        int row = nt * 16 + l15;
        bf16x8 A = *(const bf16x8*)(&Tsh[row * 128 + (((kk * 4 + quad) ^ l15) << 3)]);
        acc = __builtin_amdgcn_mfma_f32_16x16x32_bf16(A, B[kk], acc, 0, 0, 0);
      }
      #pragma unroll
      for (int r = 0; r < 4; ++r){
        int nl = nt * 16 + quad * 4 + r;
        float s = (acc[r] + u1s[nl] + u2v + c3v) * inv;
        Ssh[nl * 200 + m] = (short)f2bf(s);
      }
    }
  }
  __syncthreads();

  // ---- softmax over valid cols m<168; write P bf16 (cols 168..191 = 0) ----
  {
    float* rstat = (float*)Tsh;      // T data dead; 2304B of stats
    float* mxh  = rstat;             // [2*rows]
    float* smh  = rstat + 192;       // [2*rows]
    float* mxf  = rstat + 384;       // [rows]
    float* sinv = rstat + 480;       // [rows]
    if (t < 2 * rows){
      int r = t >> 1, hh = t & 1;
      const short* rowp = &Ssh[r * 200 + hh * 84];
      float mv = -1e30f;
      for (int m2 = 0; m2 < 84; ++m2) mv = fmaxf(mv, bf2f((unsigned short)rowp[m2]));
      mxh[t] = mv;
    }
    __syncthreads();
    if (t < rows) mxf[t] = fmaxf(mxh[2 * t], mxh[2 * t + 1]);
    __syncthreads();
    if (t < 2 * rows){
      int r = t >> 1, hh = t & 1;
      const short* rowp = &Ssh[r * 200 + hh * 84];
      float mv = mxf[r], sm = 0.f;
      for (int m2 = 0; m2 < 84; ++m2) sm += expf(bf2f((unsigned short)rowp[m2]) - mv);
      smh[t] = sm;
    }
    __syncthreads();
    if (t < rows) sinv[t] = 1.f / (smh[2 * t] + smh[2 * t + 1]);
    __syncthreads();
    for (int idx = t; idx < rows * 192; idx += 256){
      int r = idx / 192, m2 = idx - r * 192;
      short val = 0;
      if (m2 < 168){
        float s = bf2f((unsigned short)Ssh[r * 200 + m2]);
        val = (short)f2bf(expf(s - mxf[r]) * sinv[r]);
      }
      Ssh[r * 200 + m2] = val;
    }
  }
  __syncthreads();

  // ---- Phase C: U = P @ H  (write bf16 into T region, swizzled) ----
  for (int ei = 0; ei < 2; ++ei){
    const int e0 = (w * 2 + ei) * 16;
    bf16x8 B[6];
    for (int kt = 0; kt < 6; ++kt){
      bf16x8 bv;
      #pragma unroll
      for (int jj = 0; jj < 8; ++jj){
        int m = kt * 32 + quad * 8 + jj;
        bv[jj] = (m < NPAD) ? Hb[(size_t)m * 128 + e0 + l15] : (short)0;
      }
      B[kt] = bv;
    }
    for (int nt = 0; nt < NT; ++nt){
      f32x4 acc = {0.f, 0.f, 0.f, 0.f};
      #pragma unroll
      for (int kt = 0; kt < 6; ++kt){
        int row = nt * 16 + l15;
        bf16x8 A = *(const bf16x8*)(&Ssh[row * 200 + kt * 32 + quad * 8]);
        acc = __builtin_amdgcn_mfma_f32_16x16x32_bf16(A, B[kt], acc, 0, 0, 0);
      }
      const int ecol = e0 + l15, ch = ecol >> 3;
      #pragma unroll
      for (int r = 0; r < 4; ++r){
        int row = nt * 16 + quad * 4 + r;
        Tsh[row * 128 + ((ch ^ (row & 15)) << 3) + (ecol & 7)] = (short)f2bf(acc[r]);
      }
    }
  }
  __syncthreads();

  // ---- Phase D: O = U @ Wv + vb, fused FC reduction ----
  float tp = 0.f;
  for (int ei = 0; ei < 2; ++ei){
    const int e0 = (w * 2 + ei) * 16;
    bf16x8 B[4];
    #pragma unroll
    for (int kk = 0; kk < 4; ++kk)
      B[kk] = *(const bf16x8*)(WvTh + (e0 + l15) * 128 + kk * 32 + quad * 8);
    const float vbv = vb[h * 128 + e0 + l15];
    for (int nt = 0; nt < NT; ++nt){
      f32x4 acc = {0.f, 0.f, 0.f, 0.f};
      #pragma unroll
      for (int kk = 0; kk < 4; ++kk){
        int row = nt * 16 + l15;
        bf16x8 A = *(const bf16x8*)(&Tsh[row * 128 + (((kk * 4 + quad) ^ l15) << 3)]);
        acc = __builtin_amdgcn_mfma_f32_16x16x32_bf16(A, B[kk], acc, 0, 0, 0);
      }
      #pragma unroll
      for (int r = 0; r < 4; ++r){
        int ng = rowbase + nt * 16 + quad * 4 + r;
        if (ng < N)
          tp = fmaf(acc[r] + vbv, fcw[ng * 512 + h * 128 + e0 + l15], tp);
      }
    }
  }
  float tot = rsum256(tp, red4);
  if (t == 0) atomicAdd(out + b, tot);
}

} // anonymous namespace

extern "C" void kernel_launch(void* const* d_in, const int* in_sizes, int n_in,
                              void* d_out, int out_size, void* d_ws, size_t ws_size,
                              hipStream_t stream) {
  (void)in_sizes; (void)n_in; (void)out_size;
  const float* X      = (const float*)d_in[0];
  const float* spa_w1 = (const float*)d_in[1];
  const float* spa_b1 = (const float*)d_in[2];
  const float* spa_w2 = (const float*)d_in[3];
  const float* spa_b2 = (const float*)d_in[4];
  const float* tem_w1 = (const float*)d_in[5];
  const float* tem_b1 = (const float*)d_in[6];
  const float* tem_w2 = (const float*)d_in[7];
  const float* tem_b2 = (const float*)d_in[8];
  const float* sgnn_w = (const float*)d_in[9];
  const float* sgnn_b = (const float*)d_in[10];
  const float* tgnn_w = (const float*)d_in[11];
  const float* tgnn_b = (const float*)d_in[12];
  const float* q_w    = (const float*)d_in[13];
  const float* q_b    = (const float*)d_in[14];
  const float* k_w    = (const float*)d_in[15];
  const float* k_b    = (const float*)d_in[16];
  const float* v_w    = (const float*)d_in[17];
  const float* v_b    = (const float*)d_in[18];
  const float* fc_w   = (const float*)d_in[19];
  const float* fc_b   = (const float*)d_in[20];
  float* out = (float*)d_out;

  // ws layout (bytes):
  //   H fp32:   [0, 88,080,384)
  //   R region: [88,080,384, 182,714,368)
  //     phase1: Xf (20,971,520) | As (6,553,600) | At (67,108,864)
  //     phase2: Hbf bf16 1024x176x128 (46,137,344) overlapping Xf/As/At-head
  //     prep at R+46,137,344 (inside dead At): MT|WvT|c1|c2|c3 (~267 KB)
  if (ws_size < (size_t)182714368) return;

  char* wsb = (char*)d_ws;
  float* H   = (float*)wsb;
  char*  Rb  = wsb + 88080384;
  float* Xf  = (float*)Rb;
  float* As  = (float*)(Rb + 20971520);
  float* At  = (float*)(Rb + 27525120);
  short* Hbf = (short*)Rb;
  char*  Pb  = Rb + 46137344;
  short* MT  = (short*)Pb;
  short* WvT = (short*)(Pb + 131072);
  float* c1  = (float*)(Pb + 262144);
  float* c2  = (float*)(Pb + 264192);
  float* c3  = (float*)(Pb + 266240);

  feat_kernel<<<BSZ * P, 128, 0, stream>>>(X, Xf);
  cumnorm_kernel<<<BSZ, 256, 0, stream>>>(Xf);
  adjt_kernel<<<BSZ, 256, 0, stream>>>(Xf, tem_w1, tem_b1, tem_w2, tem_b2, At);
  adjs_kernel<<<BSZ, 256, 0, stream>>>(Xf, spa_w1, spa_b1, spa_w2, spa_b2, As);
  hs_kernel<<<BSZ, 256, 0, stream>>>(Xf, As, sgnn_w, sgnn_b, H);
  ht_kernel<<<BSZ, 256, 0, stream>>>(Xf, At, tgnn_w, tgnn_b, H);
  // prep/cast AFTER ht (their regions overlap dead At / Xf)
  prep_kernel<<<NH, 256, 0, stream>>>(q_w, q_b, k_w, k_b, v_w, MT, WvT, c1, c2, c3);
  cast_kernel<<<BSZ, 256, 0, stream>>>(H, Hbf);
  initout_kernel<<<4, 256, 0, stream>>>(out, fc_b);
  attn_mega<<<dim3(BSZ, NH, 2), 256, 0, stream>>>(Hbf, MT, WvT, c1, c2, c3, v_b, fc_w, out);
}

// Round 3
// 2086.826 us; speedup vs baseline: 3.8813x; 1.1742x over previous
//
#include <hip/hip_runtime.h>
#include <math.h>

namespace {

constexpr int BSZ  = 1024;
constexpr int P    = 128;
constexpr int HG   = 128;
constexpr int NH   = 4;
constexpr int N    = 168;     // P + IND
constexpr int NPAD = 176;     // padded token count (11 tiles of 16)

typedef short bf16x8 __attribute__((ext_vector_type(8)));
typedef float f32x4  __attribute__((ext_vector_type(4)));

__device__ __forceinline__ unsigned short f2bf(float x){
  union { float f; unsigned u; } v; v.f = x;
  unsigned r = (v.u + 0x7FFF + ((v.u >> 16) & 1)) >> 16;
  return (unsigned short)r;
}
__device__ __forceinline__ float bf2f(unsigned short b){
  union { unsigned u; float f; } v; v.u = ((unsigned)b) << 16;
  return v.f;
}

// ---------- wave (64-lane) butterfly reductions: result in ALL lanes ----------
__device__ __forceinline__ float wsum(float v){
  #pragma unroll
  for (int o = 1; o < 64; o <<= 1) v += __shfl_xor(v, o, 64);
  return v;
}
__device__ __forceinline__ float wmax(float v){
  #pragma unroll
  for (int o = 1; o < 64; o <<= 1) v = fmaxf(v, __shfl_xor(v, o, 64));
  return v;
}
__device__ __forceinline__ float wmin(float v){
  #pragma unroll
  for (int o = 1; o < 64; o <<= 1) v = fminf(v, __shfl_xor(v, o, 64));
  return v;
}
__device__ __forceinline__ float rsum256(float v, volatile float* red4){
  #pragma unroll
  for (int o = 32; o > 0; o >>= 1) v += __shfl_down(v, o, 64);
  __syncthreads();
  if ((threadIdx.x & 63) == 0) red4[threadIdx.x >> 6] = v;
  __syncthreads();
  return red4[0] + red4[1] + red4[2] + red4[3];
}

// ---------- K1: per-patch features, one WAVE per patch, no LDS, no barriers ----------
__global__ __launch_bounds__(256) void feat_kernel(const float* __restrict__ X,
                                                   float* __restrict__ Xf){
  const int wave = threadIdx.x >> 6, l = threadIdx.x & 63;
  const int pp = blockIdx.x * 4 + wave;          // patch id
  const float* xp = X + (size_t)pp * 128;
  const float x0 = xp[l];
  const float x1 = xp[l + 64];

  // ---- temporal ----
  float sum   = wsum(x0 + x1);
  float mean  = sum * (1.0f / 128.0f);
  float mx    = wmax(fmaxf(x0, x1));
  float mn    = wmin(fminf(x0, x1));
  float sumsq = wsum(fmaf(x0, x0, x1 * x1));
  float c0 = x0 - mean, c1_ = x1 - mean;
  float c0q = c0 * c0, c1q = c1_ * c1_;
  float m2 = wsum(c0q + c1q);
  float m3 = wsum(c0q * c0 + c1q * c1_);
  float m4 = wsum(c0q * c0q + c1q * c1q);
  float var = m2 * (1.0f / 127.0f);
  float sd  = sqrtf(var);
  float rms = sqrtf(sumsq * (1.0f / 128.0f));
  float ex0 = expf(x0 - mx), ex1 = expf(x1 - mx);
  float Z   = wsum(ex0 + ex1);
  float SxE = wsum(fmaf(ex0, x0, ex1 * x1));
  float ent = (mx + logf(Z)) - SxE / Z;
  const float lo = (float)(-1.0 + 1e-7), hi = (float)(1.0 - 1e-7);
  float a0 = asinf(fminf(fmaxf(x0, lo), hi));
  float a1 = asinf(fminf(fmaxf(x1, lo), hi));
  float amean = wsum(a0 + a1) * (1.0f / 128.0f);
  float ad0 = a0 - amean, ad1 = a1 - amean;
  float std_asin = sqrtf(wsum(fmaf(ad0, ad0, ad1 * ad1)) * (1.0f / 127.0f));
  float b0 = atanf(x0), b1v = atanf(x1);
  float bmean = wsum(b0 + b1v) * (1.0f / 128.0f);
  float bd0 = b0 - bmean, bd1 = b1v - bmean;
  float std_atan = sqrtf(wsum(fmaf(bd0, bd0, bd1 * bd1)) * (1.0f / 127.0f));
  float kurt = (m4 * (1.0f / 128.0f)) / (sd * sd * sd * sd) - 3.0f;
  float skew = (m3 * (1.0f / 128.0f)) / (sd * sd * sd);

  // ---- DFT: lane l computes bin l via rotation recurrence (64 folded steps) ----
  // fold tt & tt+64:  w(tt+64) = w(tt) * (-1)^l  ->  se = x[tt] + (-1)^l x[tt+64]
  const float sign = (l & 1) ? -1.0f : 1.0f;
  float sC, cC;
  __sincosf((float)l * 0.049087385212340517f, &sC, &cC);   // 2*pi*l/128
  const float c1r = cC, s1r = -sC;
  const int x0i = __float_as_int(x0), x1i = __float_as_int(x1);
  float re = 0.f, im = 0.f;
  float wc = 1.f, ws = 0.f;
  #pragma unroll 8
  for (int tt = 0; tt < 32; ++tt){
    float s0v = __int_as_float(__builtin_amdgcn_readlane(x0i, tt));
    float s1v = __int_as_float(__builtin_amdgcn_readlane(x1i, tt));
    float se = fmaf(sign, s1v, s0v);
    re = fmaf(se, wc, re);
    im = fmaf(se, ws, im);
    float t1 = ws * s1r, t2 = ws * c1r;
    float nwc = fmaf(wc, c1r, -t1);
    ws = fmaf(wc, s1r, t2);
    wc = nwc;
  }
  { // exact reseed at tt=32: w = e^{-i*pi*l/2}
    int lm = l & 3;
    wc = (lm == 0) ? 1.f : (lm == 2) ? -1.f : 0.f;
    ws = (lm == 1) ? -1.f : (lm == 3) ? 1.f : 0.f;
  }
  #pragma unroll 8
  for (int tt = 32; tt < 64; ++tt){
    float s0v = __int_as_float(__builtin_amdgcn_readlane(x0i, tt));
    float s1v = __int_as_float(__builtin_amdgcn_readlane(x1i, tt));
    float se = fmaf(sign, s1v, s0v);
    re = fmaf(se, wc, re);
    im = fmaf(se, ws, im);
    float t1 = ws * s1r, t2 = ws * c1r;
    float nwc = fmaf(wc, c1r, -t1);
    ws = fmaf(wc, s1r, t2);
    wc = nwc;
  }
  float psd = fmaf(re, re, im * im) * 0.0078125f;          // bins 0..63 (lane l)
  float re64 = wsum(sign * (x0 + x1));                     // bin 64
  float psd64 = re64 * re64 * 0.0078125f;
  // full 128-bin array = [psd_0..psd_63, psd64, psd_63..psd_1] (exact mirror)

  const float mult = (l == 0) ? 1.f : 2.f;
  float psum = wsum(psd * mult) + psd64;
  float p2   = wsum(psd * psd * mult) + psd64 * psd64;
  float vm   = wmax(psd);
  float maxp = fmaxf(vm, psd64);
  // mean_freq numerator: pair terms (+k/128, -k/128) cancel exactly -> only bin 64
  float meanfreq = (-0.5f * psd64) / psum;
  float pbw = sqrtf(p2 / psum);
  float cand = (psd == vm) ? (float)l : 1e9f;              // first-index argmax
  float lminf = wmin(cand);
  float fmaxv = (psd64 > vm) ? -0.5f : lminf * (1.0f / 128.0f);
  float maxamp = sqrtf(maxp * 128.0f);

  // ---- median (stable rank 64 of 128, multiplicity-aware ballot rank) ----
  // element k (k=0..63) has count less_k; element 128-k has count less_k + 1
  float med = -0.5f;
  for (int kt = 0; kt < 64; ++kt){
    float vt = __int_as_float(__builtin_amdgcn_readlane(__float_as_int(psd), kt));
    unsigned long long mask = __ballot(psd < vt);
    int less = 2 * __popcll(mask) - (int)(mask & 1ull) + ((psd64 < vt) ? 1 : 0);
    if (less == 64) med = (float)kt * (1.0f / 128.0f);
    else if (less == 63 && kt >= 1) med = -(float)kt * (1.0f / 128.0f);
  }
  {
    unsigned long long mask = __ballot(psd < psd64);
    int less = 2 * __popcll(mask) - (int)(mask & 1ull);
    if (less == 64) med = -0.5f;
  }

  if (l == 0){
    float* o = Xf + (size_t)pp * 40;
    o[0]  = mx;  o[1]  = mn;  o[2]  = sd;   o[3]  = rms; o[4]  = mean;
    o[5]  = mx - mn;  o[6] = var;  o[7] = ent; o[8] = std_asin; o[9] = std_atan;
    o[10] = kurt; o[11] = skew;
    o[12] = meanfreq;
    o[13] = med;
    o[14] = psum;
    o[15] = 1.0f;
    o[16] = pbw;
    o[17] = maxp;
    o[18] = maxamp;
    o[19] = fmaxv;
  }
}

// ---------- K2: cumsum feature + per-sample normalization ----------
__global__ __launch_bounds__(256) void cumnorm_kernel(float* __restrict__ Xf){
  const int b = blockIdx.x, t = threadIdx.x;
  __shared__ float arr[128 * 40];
  __shared__ float red4[4];
  float* base = Xf + b * 5120;
  for (int idx = t; idx < 128 * 20; idx += 256){
    int p = idx / 20, c = idx - p * 20;
    arr[p * 40 + c] = base[p * 40 + c];
  }
  __syncthreads();
  if (t < 20){
    float acc = 0.f;
    for (int p = 0; p < 128; ++p){
      acc += arr[p * 40 + t];
      arr[p * 40 + 20 + t] = acc / sqrtf(fmaxf(fabsf(acc), 1e-12f));
    }
  }
  __syncthreads();
  float pa = 0.f;
  for (int idx = t; idx < 5120; idx += 256){ float v = arr[idx]; pa = fmaf(v, v, pa); }
  float nrm = sqrtf(rsum256(pa, red4));
  for (int idx = t; idx < 5120; idx += 256) base[idx] = arr[idx] / nrm;
}

// ---------- K3: A_t ----------
__global__ __launch_bounds__(256) void adjt_kernel(const float* __restrict__ Xf,
    const float* __restrict__ w1, const float* __restrict__ b1,
    const float* __restrict__ w2, const float* __restrict__ b2,
    float* __restrict__ At){
  const int b = blockIdx.x, t = threadIdx.x;
  __shared__ float xf[5120];
  __shared__ float T[128 * 64];
  const float* src = Xf + b * 5120;
  for (int idx = t; idx < 5120; idx += 256) xf[idx] = src[idx];
  __syncthreads();
  for (int idx = t; idx < 128 * 64; idx += 256){
    int i = idx >> 6, k = idx & 63;
    float acc = b1[k];
    #pragma unroll 8
    for (int c = 0; c < 40; ++c) acc = fmaf(xf[i * 40 + c], w1[c * 64 + k], acc);
    T[idx] = tanhf(acc);
  }
  __syncthreads();
  float* dst = At + b * 16384;
  for (int idx = t; idx < 16384; idx += 256){
    int i = idx >> 7, j = idx & 127;
    float acc = b2[j];
    #pragma unroll 8
    for (int k = 0; k < 64; ++k) acc = fmaf(T[i * 64 + k], w2[k * 128 + j], acc);
    dst[idx] = acc;
  }
}

// ---------- K4: A_s ----------
__global__ __launch_bounds__(256) void adjs_kernel(const float* __restrict__ Xf,
    const float* __restrict__ w1, const float* __restrict__ b1,
    const float* __restrict__ w2, const float* __restrict__ b2,
    float* __restrict__ As){
  const int b = blockIdx.x, t = threadIdx.x;
  __shared__ float xf[5120];
  __shared__ float T2[40 * 64];
  const float* src = Xf + b * 5120;
  for (int idx = t; idx < 5120; idx += 256) xf[idx] = src[idx];
  __syncthreads();
  for (int idx = t; idx < 40 * 64; idx += 256){
    int i = idx >> 6, k = idx & 63;
    float acc = b1[k];
    for (int p = 0; p < 128; ++p) acc = fmaf(xf[p * 40 + i], w1[p * 64 + k], acc);
    T2[idx] = tanhf(acc);
  }
  __syncthreads();
  float* dst = As + b * 1600;
  for (int idx = t; idx < 1600; idx += 256){
    int i = idx / 40, j = idx - i * 40;
    float acc = b2[j];
    #pragma unroll 8
    for (int k = 0; k < 64; ++k) acc = fmaf(T2[i * 64 + k], w2[k * 40 + j], acc);
    dst[idx] = acc;
  }
}

// ---------- K5: H_s ----------
__global__ __launch_bounds__(256) void hs_kernel(const float* __restrict__ Xf,
    const float* __restrict__ As_g, const float* __restrict__ w, const float* __restrict__ bias,
    float* __restrict__ H){
  const int b = blockIdx.x, t = threadIdx.x;
  __shared__ float xf[128 * 41];
  __shared__ float As[1600];
  __shared__ float M[40 * 128];
  const float* src = Xf + b * 5120;
  for (int idx = t; idx < 5120; idx += 256){ int p = idx / 40, c = idx - p * 40; xf[p * 41 + c] = src[idx]; }
  for (int idx = t; idx < 1600; idx += 256) As[idx] = As_g[b * 1600 + idx];
  __syncthreads();
  for (int idx = t; idx < 5120; idx += 256){
    int i = idx >> 7, p = idx & 127;
    float acc = 0.f;
    #pragma unroll 8
    for (int m = 0; m < 40; ++m) acc = fmaf(As[i * 40 + m], xf[p * 41 + m], acc);
    M[i * 128 + p] = acc;
  }
  __syncthreads();
  float* dst = H + (size_t)b * (N * HG);
  for (int idx = t; idx < 5120; idx += 256){
    int i = idx >> 7, j = idx & 127;
    float acc = bias[j];
    for (int p = 0; p < 128; ++p) acc = fmaf(M[i * 128 + p], w[p * 128 + j], acc);
    dst[i * 128 + j] = (acc >= 0.f) ? acc : 0.01f * acc;
  }
}

// ---------- K6: H_t ----------
__global__ __launch_bounds__(256) void ht_kernel(const float* __restrict__ Xf,
    const float* __restrict__ At_g, const float* __restrict__ w, const float* __restrict__ bias,
    float* __restrict__ H){
  const int b = blockIdx.x, t = threadIdx.x;
  __shared__ float xf[128 * 41];
  __shared__ float M2[128 * 40];
  const float* src = Xf + b * 5120;
  for (int idx = t; idx < 5120; idx += 256){ int p = idx / 40, c = idx - p * 40; xf[p * 41 + c] = src[idx]; }
  __syncthreads();
  const float* At = At_g + (size_t)b * 16384;
  for (int idx = t; idx < 5120; idx += 256){
    int i = idx / 40, c = idx - i * 40;
    float acc = 0.f;
    for (int m = 0; m < 128; ++m) acc = fmaf(At[i * 128 + m], xf[m * 41 + c], acc);
    M2[i * 40 + c] = acc;
  }
  __syncthreads();
  float* dst = H + (size_t)b * (N * HG) + 40 * 128;
  for (int idx = t; idx < 16384; idx += 256){
    int i = idx >> 7, j = idx & 127;
    float acc = bias[j];
    #pragma unroll 8
    for (int c = 0; c < 40; ++c) acc = fmaf(M2[i * 40 + c], w[c * 128 + j], acc);
    dst[i * 128 + j] = (acc >= 0.f) ? acc : 0.01f * acc;
  }
}

__global__ void initout_kernel(float* __restrict__ out, const float* __restrict__ fcb){
  int i = blockIdx.x * 256 + threadIdx.x;
  if (i < BSZ) out[i] = fcb[0];
}

// ---------- prep: per-head M^T = (Wq Wk^T)^T, Wv^T, c1/c2/c3 (bf16 weights) ----------
__global__ __launch_bounds__(256) void prep_kernel(
    const float* __restrict__ qw, const float* __restrict__ qb,
    const float* __restrict__ kw, const float* __restrict__ kb,
    const float* __restrict__ vw,
    short* __restrict__ MT, short* __restrict__ WvT,
    float* __restrict__ c1, float* __restrict__ c2, float* __restrict__ c3){
  const int h = blockIdx.x, t = threadIdx.x;
  const float* Q = qw + h * 16384;
  const float* K = kw + h * 16384;
  const float* V = vw + h * 16384;
  for (int idx = t; idx < 16384; idx += 256){
    int j = idx >> 7, d = idx & 127;
    float acc = 0.f;
    for (int e = 0; e < 128; ++e) acc = fmaf(Q[d * 128 + e], K[j * 128 + e], acc);
    MT[h * 16384 + j * 128 + d] = (short)f2bf(acc);     // MT[j][d] = M[d][j]
  }
  for (int idx = t; idx < 16384; idx += 256){
    int e = idx >> 7, d = idx & 127;
    WvT[h * 16384 + idx] = (short)f2bf(V[d * 128 + e]); // WvT[e][d] = Wv[d][e]
  }
  if (t < 128){
    float a = 0.f, bsum = 0.f;
    for (int e = 0; e < 128; ++e){
      a    = fmaf(Q[t * 128 + e], kb[h * 128 + e], a);
      bsum = fmaf(K[t * 128 + e], qb[h * 128 + e], bsum);
    }
    c1[h * 128 + t] = a;
    c2[h * 128 + t] = bsum;
  }
  if (t == 128){
    float a = 0.f;
    for (int e = 0; e < 128; ++e) a = fmaf(qb[h * 128 + e], kb[h * 128 + e], a);
    c3[h] = a;
  }
}

// ---------- cast H -> bf16 with zero-padded rows 168..175 ----------
__global__ __launch_bounds__(256) void cast_kernel(const float* __restrict__ H,
                                                   short* __restrict__ Hbf){
  const int b = blockIdx.x;
  for (int idx = threadIdx.x; idx < NPAD * 128; idx += 256){
    int n = idx >> 7, d = idx & 127;
    float v = (n < N) ? H[((size_t)b * N + n) * 128 + d] : 0.f;
    Hbf[(size_t)b * NPAD * 128 + idx] = (short)f2bf(v);
  }
}

// ---------- attention mega-kernel ----------
__global__ __launch_bounds__(256) void attn_mega(
    const short* __restrict__ Hbf, const short* __restrict__ MT,
    const short* __restrict__ WvT, const float* __restrict__ c1g,
    const float* __restrict__ c2g, const float* __restrict__ c3g,
    const float* __restrict__ vb, const float* __restrict__ fcw,
    float* __restrict__ out){
  const int b = blockIdx.x, h = blockIdx.y, z = blockIdx.z;
  const int rowbase = z * 96;
  const int rows = z ? 80 : 96;
  const int NT = z ? 5 : 6;
  const int t = threadIdx.x;
  const int w = t >> 6, l = t & 63, quad = l >> 4, l15 = l & 15;

  __shared__ __align__(16) short Tsh[96 * 128];   // T then U (XOR-swizzled rows)
  __shared__ __align__(16) short Ssh[96 * 200];   // S then P (bf16, stride 200)
  __shared__ float u1s[96];
  __shared__ float u2s[176];
  __shared__ float red4[4];

  const short* Hb = Hbf + (size_t)b * NPAD * 128;
  const short* MTh = MT + h * 16384;
  const short* WvTh = WvT + h * 16384;
  const float c3v = c3g[h];
  const float inv = 0.08838834764831845f;   // 1/sqrt(128)

  // stage c1,c2 into (dead) T region
  float* stage = (float*)Tsh;
  if (t < 128) stage[t] = c1g[h * 128 + t];
  else stage[t] = c2g[h * 128 + (t - 128)];
  __syncthreads();

  if (t < 176){
    float acc = 0.f;
    const bf16x8* rp = (const bf16x8*)(Hb + (size_t)t * 128);
    for (int kk = 0; kk < 16; ++kk){
      bf16x8 v = rp[kk];
      #pragma unroll
      for (int j = 0; j < 8; ++j)
        acc = fmaf(bf2f((unsigned short)v[j]), stage[128 + kk * 8 + j], acc);
    }
    u2s[t] = acc;
  }
  if (t < rows){
    float acc = 0.f;
    const bf16x8* rp = (const bf16x8*)(Hb + (size_t)(rowbase + t) * 128);
    for (int kk = 0; kk < 16; ++kk){
      bf16x8 v = rp[kk];
      #pragma unroll
      for (int j = 0; j < 8; ++j)
        acc = fmaf(bf2f((unsigned short)v[j]), stage[kk * 8 + j], acc);
    }
    u1s[t] = acc;
  }
  __syncthreads();

  // ---- Phase A: T = H_rows @ M ----
  for (int jt = 0; jt < 2; ++jt){
    const int j0 = (w * 2 + jt) * 16;
    bf16x8 B[4];
    #pragma unroll
    for (int kk = 0; kk < 4; ++kk)
      B[kk] = *(const bf16x8*)(MTh + (j0 + l15) * 128 + kk * 32 + quad * 8);
    for (int nt = 0; nt < NT; ++nt){
      f32x4 acc = {0.f, 0.f, 0.f, 0.f};
      #pragma unroll
      for (int kk = 0; kk < 4; ++kk){
        bf16x8 A = *(const bf16x8*)(Hb + (size_t)(rowbase + nt * 16 + l15) * 128 + kk * 32 + quad * 8);
        acc = __builtin_amdgcn_mfma_f32_16x16x32_bf16(A, B[kk], acc, 0, 0, 0);
      }
      const int jcol = j0 + l15, ch = jcol >> 3;
      #pragma unroll
      for (int r = 0; r < 4; ++r){
        int row = nt * 16 + quad * 4 + r;
        Tsh[row * 128 + ((ch ^ (row & 15)) << 3) + (jcol & 7)] = (short)f2bf(acc[r]);
      }
    }
  }
  __syncthreads();

  // ---- Phase B: S = T @ H^T (+rank-1 terms) ----
  for (int mi = 0; mi < 3; ++mi){
    const int mt = w + mi * 4;
    if (mt >= 11) break;
    const int m0 = mt * 16;
    bf16x8 B[4];
    #pragma unroll
    for (int kk = 0; kk < 4; ++kk)
      B[kk] = *(const bf16x8*)(Hb + (size_t)(m0 + l15) * 128 + kk * 32 + quad * 8);
    const int m = m0 + l15;
    const float u2v = u2s[m];
    for (int nt = 0; nt < NT; ++nt){
      f32x4 acc = {0.f, 0.f, 0.f, 0.f};
      #pragma unroll
      for (int kk = 0; kk < 4; ++kk){
        int row = nt * 16 + l15;
        bf16x8 A = *(const bf16x8*)(&Tsh[row * 128 + (((kk * 4 + quad) ^ l15) << 3)]);
        acc = __builtin_amdgcn_mfma_f32_16x16x32_bf16(A, B[kk], acc, 0, 0, 0);
      }
      #pragma unroll
      for (int r = 0; r < 4; ++r){
        int nl = nt * 16 + quad * 4 + r;
        float s = (acc[r] + u1s[nl] + u2v + c3v) * inv;
        Ssh[nl * 200 + m] = (short)f2bf(s);
      }
    }
  }
  __syncthreads();

  // ---- softmax ----
  {
    float* rstat = (float*)Tsh;
    float* mxh  = rstat;
    float* smh  = rstat + 192;
    float* mxf  = rstat + 384;
    float* sinv = rstat + 480;
    if (t < 2 * rows){
      int r = t >> 1, hh = t & 1;
      const short* rowp = &Ssh[r * 200 + hh * 84];
      float mv = -1e30f;
      for (int m2 = 0; m2 < 84; ++m2) mv = fmaxf(mv, bf2f((unsigned short)rowp[m2]));
      mxh[t] = mv;
    }
    __syncthreads();
    if (t < rows) mxf[t] = fmaxf(mxh[2 * t], mxh[2 * t + 1]);
    __syncthreads();
    if (t < 2 * rows){
      int r = t >> 1, hh = t & 1;
      const short* rowp = &Ssh[r * 200 + hh * 84];
      float mv = mxf[r], sm = 0.f;
      for (int m2 = 0; m2 < 84; ++m2) sm += expf(bf2f((unsigned short)rowp[m2]) - mv);
      smh[t] = sm;
    }
    __syncthreads();
    if (t < rows) sinv[t] = 1.f / (smh[2 * t] + smh[2 * t + 1]);
    __syncthreads();
    for (int idx = t; idx < rows * 192; idx += 256){
      int r = idx / 192, m2 = idx - r * 192;
      short val = 0;
      if (m2 < 168){
        float s = bf2f((unsigned short)Ssh[r * 200 + m2]);
        val = (short)f2bf(expf(s - mxf[r]) * sinv[r]);
      }
      Ssh[r * 200 + m2] = val;
    }
  }
  __syncthreads();

  // ---- Phase C: U = P @ H ----
  for (int ei = 0; ei < 2; ++ei){
    const int e0 = (w * 2 + ei) * 16;
    bf16x8 B[6];
    for (int kt = 0; kt < 6; ++kt){
      bf16x8 bv;
      #pragma unroll
      for (int jj = 0; jj < 8; ++jj){
        int m = kt * 32 + quad * 8 + jj;
        bv[jj] = (m < NPAD) ? Hb[(size_t)m * 128 + e0 + l15] : (short)0;
      }
      B[kt] = bv;
    }
    for (int nt = 0; nt < NT; ++nt){
      f32x4 acc = {0.f, 0.f, 0.f, 0.f};
      #pragma unroll
      for (int kt = 0; kt < 6; ++kt){
        int row = nt * 16 + l15;
        bf16x8 A = *(const bf16x8*)(&Ssh[row * 200 + kt * 32 + quad * 8]);
        acc = __builtin_amdgcn_mfma_f32_16x16x32_bf16(A, B[kt], acc, 0, 0, 0);
      }
      const int ecol = e0 + l15, ch = ecol >> 3;
      #pragma unroll
      for (int r = 0; r < 4; ++r){
        int row = nt * 16 + quad * 4 + r;
        Tsh[row * 128 + ((ch ^ (row & 15)) << 3) + (ecol & 7)] = (short)f2bf(acc[r]);
      }
    }
  }
  __syncthreads();

  // ---- Phase D: O = U @ Wv + vb, fused FC reduction ----
  float tp = 0.f;
  for (int ei = 0; ei < 2; ++ei){
    const int e0 = (w * 2 + ei) * 16;
    bf16x8 B[4];
    #pragma unroll
    for (int kk = 0; kk < 4; ++kk)
      B[kk] = *(const bf16x8*)(WvTh + (e0 + l15) * 128 + kk * 32 + quad * 8);
    const float vbv = vb[h * 128 + e0 + l15];
    for (int nt = 0; nt < NT; ++nt){
      f32x4 acc = {0.f, 0.f, 0.f, 0.f};
      #pragma unroll
      for (int kk = 0; kk < 4; ++kk){
        int row = nt * 16 + l15;
        bf16x8 A = *(const bf16x8*)(&Tsh[row * 128 + (((kk * 4 + quad) ^ l15) << 3)]);
        acc = __builtin_amdgcn_mfma_f32_16x16x32_bf16(A, B[kk], acc, 0, 0, 0);
      }
      #pragma unroll
      for (int r = 0; r < 4; ++r){
        int ng = rowbase + nt * 16 + quad * 4 + r;
        if (ng < N)
          tp = fmaf(acc[r] + vbv, fcw[ng * 512 + h * 128 + e0 + l15], tp);
      }
    }
  }
  float tot = rsum256(tp, red4);
  if (t == 0) atomicAdd(out + b, tot);
}

} // anonymous namespace

extern "C" void kernel_launch(void* const* d_in, const int* in_sizes, int n_in,
                              void* d_out, int out_size, void* d_ws, size_t ws_size,
                              hipStream_t stream) {
  (void)in_sizes; (void)n_in; (void)out_size;
  const float* X      = (const float*)d_in[0];
  const float* spa_w1 = (const float*)d_in[1];
  const float* spa_b1 = (const float*)d_in[2];
  const float* spa_w2 = (const float*)d_in[3];
  const float* spa_b2 = (const float*)d_in[4];
  const float* tem_w1 = (const float*)d_in[5];
  const float* tem_b1 = (const float*)d_in[6];
  const float* tem_w2 = (const float*)d_in[7];
  const float* tem_b2 = (const float*)d_in[8];
  const float* sgnn_w = (const float*)d_in[9];
  const float* sgnn_b = (const float*)d_in[10];
  const float* tgnn_w = (const float*)d_in[11];
  const float* tgnn_b = (const float*)d_in[12];
  const float* q_w    = (const float*)d_in[13];
  const float* q_b    = (const float*)d_in[14];
  const float* k_w    = (const float*)d_in[15];
  const float* k_b    = (const float*)d_in[16];
  const float* v_w    = (const float*)d_in[17];
  const float* v_b    = (const float*)d_in[18];
  const float* fc_w   = (const float*)d_in[19];
  const float* fc_b   = (const float*)d_in[20];
  float* out = (float*)d_out;

  if (ws_size < (size_t)182714368) return;

  char* wsb = (char*)d_ws;
  float* H   = (float*)wsb;
  char*  Rb  = wsb + 88080384;
  float* Xf  = (float*)Rb;
  float* As  = (float*)(Rb + 20971520);
  float* At  = (float*)(Rb + 27525120);
  short* Hbf = (short*)Rb;
  char*  Pb  = Rb + 46137344;
  short* MT  = (short*)Pb;
  short* WvT = (short*)(Pb + 131072);
  float* c1  = (float*)(Pb + 262144);
  float* c2  = (float*)(Pb + 264192);
  float* c3  = (float*)(Pb + 266240);

  feat_kernel<<<BSZ * P / 4, 256, 0, stream>>>(X, Xf);
  cumnorm_kernel<<<BSZ, 256, 0, stream>>>(Xf);
  adjt_kernel<<<BSZ, 256, 0, stream>>>(Xf, tem_w1, tem_b1, tem_w2, tem_b2, At);
  adjs_kernel<<<BSZ, 256, 0, stream>>>(Xf, spa_w1, spa_b1, spa_w2, spa_b2, As);
  hs_kernel<<<BSZ, 256, 0, stream>>>(Xf, As, sgnn_w, sgnn_b, H);
  ht_kernel<<<BSZ, 256, 0, stream>>>(Xf, At, tgnn_w, tgnn_b, H);
  prep_kernel<<<NH, 256, 0, stream>>>(q_w, q_b, k_w, k_b, v_w, MT, WvT, c1, c2, c3);
  cast_kernel<<<BSZ, 256, 0, stream>>>(H, Hbf);
  initout_kernel<<<4, 256, 0, stream>>>(out, fc_b);
  attn_mega<<<dim3(BSZ, NH, 2), 256, 0, stream>>>(Hbf, MT, WvT, c1, c2, c3, v_b, fc_w, out);
}

// Round 4
// 1768.576 us; speedup vs baseline: 4.5797x; 1.1799x over previous
//
#include <hip/hip_runtime.h>
#include <math.h>

namespace {

constexpr int BSZ  = 1024;
constexpr int P    = 128;
constexpr int HG   = 128;
constexpr int NH   = 4;
constexpr int N    = 168;     // P + IND
constexpr int NPAD = 176;     // padded token count (11 tiles of 16)

typedef short bf16x8 __attribute__((ext_vector_type(8)));
typedef float f32x4  __attribute__((ext_vector_type(4)));

__device__ __forceinline__ unsigned short f2bf(float x){
  union { float f; unsigned u; } v; v.f = x;
  unsigned r = (v.u + 0x7FFF + ((v.u >> 16) & 1)) >> 16;
  return (unsigned short)r;
}
__device__ __forceinline__ float bf2f(unsigned short b){
  union { unsigned u; float f; } v; v.u = ((unsigned)b) << 16;
  return v.f;
}

// ---------- wave (64-lane) butterfly reductions: result in ALL lanes ----------
__device__ __forceinline__ float wsum(float v){
  #pragma unroll
  for (int o = 1; o < 64; o <<= 1) v += __shfl_xor(v, o, 64);
  return v;
}
__device__ __forceinline__ float wmax(float v){
  #pragma unroll
  for (int o = 1; o < 64; o <<= 1) v = fmaxf(v, __shfl_xor(v, o, 64));
  return v;
}
__device__ __forceinline__ float wmin(float v){
  #pragma unroll
  for (int o = 1; o < 64; o <<= 1) v = fminf(v, __shfl_xor(v, o, 64));
  return v;
}
__device__ __forceinline__ float rsum256(float v, volatile float* red4){
  #pragma unroll
  for (int o = 32; o > 0; o >>= 1) v += __shfl_down(v, o, 64);
  __syncthreads();
  if ((threadIdx.x & 63) == 0) red4[threadIdx.x >> 6] = v;
  __syncthreads();
  return red4[0] + red4[1] + red4[2] + red4[3];
}

// ---------- K1: per-patch features, one WAVE per patch, no LDS, no barriers ----------
__global__ __launch_bounds__(256) void feat_kernel(const float* __restrict__ X,
                                                   float* __restrict__ Xf){
  const int wave = threadIdx.x >> 6, l = threadIdx.x & 63;
  const int pp = blockIdx.x * 4 + wave;          // patch id
  const float* xp = X + (size_t)pp * 128;
  const float x0 = xp[l];
  const float x1 = xp[l + 64];

  // ---- temporal ----
  float sum   = wsum(x0 + x1);
  float mean  = sum * (1.0f / 128.0f);
  float mx    = wmax(fmaxf(x0, x1));
  float mn    = wmin(fminf(x0, x1));
  float sumsq = wsum(fmaf(x0, x0, x1 * x1));
  float c0 = x0 - mean, c1_ = x1 - mean;
  float c0q = c0 * c0, c1q = c1_ * c1_;
  float m2 = wsum(c0q + c1q);
  float m3 = wsum(c0q * c0 + c1q * c1_);
  float m4 = wsum(c0q * c0q + c1q * c1q);
  float var = m2 * (1.0f / 127.0f);
  float sd  = sqrtf(var);
  float rms = sqrtf(sumsq * (1.0f / 128.0f));
  float ex0 = expf(x0 - mx), ex1 = expf(x1 - mx);
  float Z   = wsum(ex0 + ex1);
  float SxE = wsum(fmaf(ex0, x0, ex1 * x1));
  float ent = (mx + logf(Z)) - SxE / Z;
  const float lo = (float)(-1.0 + 1e-7), hi = (float)(1.0 - 1e-7);
  float a0 = asinf(fminf(fmaxf(x0, lo), hi));
  float a1 = asinf(fminf(fmaxf(x1, lo), hi));
  float amean = wsum(a0 + a1) * (1.0f / 128.0f);
  float ad0 = a0 - amean, ad1 = a1 - amean;
  float std_asin = sqrtf(wsum(fmaf(ad0, ad0, ad1 * ad1)) * (1.0f / 127.0f));
  float b0 = atanf(x0), b1v = atanf(x1);
  float bmean = wsum(b0 + b1v) * (1.0f / 128.0f);
  float bd0 = b0 - bmean, bd1 = b1v - bmean;
  float std_atan = sqrtf(wsum(fmaf(bd0, bd0, bd1 * bd1)) * (1.0f / 127.0f));
  float kurt = (m4 * (1.0f / 128.0f)) / (sd * sd * sd * sd) - 3.0f;
  float skew = (m3 * (1.0f / 128.0f)) / (sd * sd * sd);

  // ---- DFT: lane l computes bin l via rotation recurrence (64 folded steps) ----
  const float sign = (l & 1) ? -1.0f : 1.0f;
  float sC, cC;
  __sincosf((float)l * 0.049087385212340517f, &sC, &cC);   // 2*pi*l/128
  const float c1r = cC, s1r = -sC;
  const int x0i = __float_as_int(x0), x1i = __float_as_int(x1);
  float re = 0.f, im = 0.f;
  float wc = 1.f, ws = 0.f;
  #pragma unroll 8
  for (int tt = 0; tt < 32; ++tt){
    float s0v = __int_as_float(__builtin_amdgcn_readlane(x0i, tt));
    float s1v = __int_as_float(__builtin_amdgcn_readlane(x1i, tt));
    float se = fmaf(sign, s1v, s0v);
    re = fmaf(se, wc, re);
    im = fmaf(se, ws, im);
    float t1 = ws * s1r, t2 = ws * c1r;
    float nwc = fmaf(wc, c1r, -t1);
    ws = fmaf(wc, s1r, t2);
    wc = nwc;
  }
  { // exact reseed at tt=32: w = e^{-i*pi*l/2}
    int lm = l & 3;
    wc = (lm == 0) ? 1.f : (lm == 2) ? -1.f : 0.f;
    ws = (lm == 1) ? -1.f : (lm == 3) ? 1.f : 0.f;
  }
  #pragma unroll 8
  for (int tt = 32; tt < 64; ++tt){
    float s0v = __int_as_float(__builtin_amdgcn_readlane(x0i, tt));
    float s1v = __int_as_float(__builtin_amdgcn_readlane(x1i, tt));
    float se = fmaf(sign, s1v, s0v);
    re = fmaf(se, wc, re);
    im = fmaf(se, ws, im);
    float t1 = ws * s1r, t2 = ws * c1r;
    float nwc = fmaf(wc, c1r, -t1);
    ws = fmaf(wc, s1r, t2);
    wc = nwc;
  }
  float psd = fmaf(re, re, im * im) * 0.0078125f;          // bins 0..63 (lane l)
  float re64 = wsum(sign * (x0 + x1));                     // bin 64
  float psd64 = re64 * re64 * 0.0078125f;

  const float mult = (l == 0) ? 1.f : 2.f;
  float psum = wsum(psd * mult) + psd64;
  float p2   = wsum(psd * psd * mult) + psd64 * psd64;
  float vm   = wmax(psd);
  float maxp = fmaxf(vm, psd64);
  float meanfreq = (-0.5f * psd64) / psum;
  float pbw = sqrtf(p2 / psum);
  float cand = (psd == vm) ? (float)l : 1e9f;              // first-index argmax
  float lminf = wmin(cand);
  float fmaxv = (psd64 > vm) ? -0.5f : lminf * (1.0f / 128.0f);
  float maxamp = sqrtf(maxp * 128.0f);

  // ---- median (stable rank 64 of 128, multiplicity-aware ballot rank) ----
  float med = -0.5f;
  for (int kt = 0; kt < 64; ++kt){
    float vt = __int_as_float(__builtin_amdgcn_readlane(__float_as_int(psd), kt));
    unsigned long long mask = __ballot(psd < vt);
    int less = 2 * __popcll(mask) - (int)(mask & 1ull) + ((psd64 < vt) ? 1 : 0);
    if (less == 64) med = (float)kt * (1.0f / 128.0f);
    else if (less == 63 && kt >= 1) med = -(float)kt * (1.0f / 128.0f);
  }
  {
    unsigned long long mask = __ballot(psd < psd64);
    int less = 2 * __popcll(mask) - (int)(mask & 1ull);
    if (less == 64) med = -0.5f;
  }

  if (l == 0){
    float* o = Xf + (size_t)pp * 40;
    o[0]  = mx;  o[1]  = mn;  o[2]  = sd;   o[3]  = rms; o[4]  = mean;
    o[5]  = mx - mn;  o[6] = var;  o[7] = ent; o[8] = std_asin; o[9] = std_atan;
    o[10] = kurt; o[11] = skew;
    o[12] = meanfreq;
    o[13] = med;
    o[14] = psum;
    o[15] = 1.0f;
    o[16] = pbw;
    o[17] = maxp;
    o[18] = maxamp;
    o[19] = fmaxv;
  }
}

// ---------- K2: cumsum feature + per-sample normalization ----------
__global__ __launch_bounds__(256) void cumnorm_kernel(float* __restrict__ Xf){
  const int b = blockIdx.x, t = threadIdx.x;
  __shared__ float arr[128 * 40];
  __shared__ float red4[4];
  float* base = Xf + b * 5120;
  for (int idx = t; idx < 128 * 20; idx += 256){
    int p = idx / 20, c = idx - p * 20;
    arr[p * 40 + c] = base[p * 40 + c];
  }
  __syncthreads();
  if (t < 20){
    float acc = 0.f;
    for (int p = 0; p < 128; ++p){
      acc += arr[p * 40 + t];
      arr[p * 40 + 20 + t] = acc / sqrtf(fmaxf(fabsf(acc), 1e-12f));
    }
  }
  __syncthreads();
  float pa = 0.f;
  for (int idx = t; idx < 5120; idx += 256){ float v = arr[idx]; pa = fmaf(v, v, pa); }
  float nrm = sqrtf(rsum256(pa, red4));
  for (int idx = t; idx < 5120; idx += 256) base[idx] = arr[idx] / nrm;
}

// ---------- K3: A_t ----------
__global__ __launch_bounds__(256) void adjt_kernel(const float* __restrict__ Xf,
    const float* __restrict__ w1, const float* __restrict__ b1,
    const float* __restrict__ w2, const float* __restrict__ b2,
    float* __restrict__ At){
  const int b = blockIdx.x, t = threadIdx.x;
  __shared__ float xf[5120];
  __shared__ float T[128 * 64];
  const float* src = Xf + b * 5120;
  for (int idx = t; idx < 5120; idx += 256) xf[idx] = src[idx];
  __syncthreads();
  for (int idx = t; idx < 128 * 64; idx += 256){
    int i = idx >> 6, k = idx & 63;
    float acc = b1[k];
    #pragma unroll 8
    for (int c = 0; c < 40; ++c) acc = fmaf(xf[i * 40 + c], w1[c * 64 + k], acc);
    T[idx] = tanhf(acc);
  }
  __syncthreads();
  float* dst = At + b * 16384;
  for (int idx = t; idx < 16384; idx += 256){
    int i = idx >> 7, j = idx & 127;
    float acc = b2[j];
    #pragma unroll 8
    for (int k = 0; k < 64; ++k) acc = fmaf(T[i * 64 + k], w2[k * 128 + j], acc);
    dst[idx] = acc;
  }
}

// ---------- K4: A_s ----------
__global__ __launch_bounds__(256) void adjs_kernel(const float* __restrict__ Xf,
    const float* __restrict__ w1, const float* __restrict__ b1,
    const float* __restrict__ w2, const float* __restrict__ b2,
    float* __restrict__ As){
  const int b = blockIdx.x, t = threadIdx.x;
  __shared__ float xf[5120];
  __shared__ float T2[40 * 64];
  const float* src = Xf + b * 5120;
  for (int idx = t; idx < 5120; idx += 256) xf[idx] = src[idx];
  __syncthreads();
  for (int idx = t; idx < 40 * 64; idx += 256){
    int i = idx >> 6, k = idx & 63;
    float acc = b1[k];
    for (int p = 0; p < 128; ++p) acc = fmaf(xf[p * 40 + i], w1[p * 64 + k], acc);
    T2[idx] = tanhf(acc);
  }
  __syncthreads();
  float* dst = As + b * 1600;
  for (int idx = t; idx < 1600; idx += 256){
    int i = idx / 40, j = idx - i * 40;
    float acc = b2[j];
    #pragma unroll 8
    for (int k = 0; k < 64; ++k) acc = fmaf(T2[i * 64 + k], w2[k * 40 + j], acc);
    dst[idx] = acc;
  }
}

// ---------- K5: H_s ----------
__global__ __launch_bounds__(256) void hs_kernel(const float* __restrict__ Xf,
    const float* __restrict__ As_g, const float* __restrict__ w, const float* __restrict__ bias,
    float* __restrict__ H){
  const int b = blockIdx.x, t = threadIdx.x;
  __shared__ float xf[128 * 41];
  __shared__ float As[1600];
  __shared__ float M[40 * 128];
  const float* src = Xf + b * 5120;
  for (int idx = t; idx < 5120; idx += 256){ int p = idx / 40, c = idx - p * 40; xf[p * 41 + c] = src[idx]; }
  for (int idx = t; idx < 1600; idx += 256) As[idx] = As_g[b * 1600 + idx];
  __syncthreads();
  for (int idx = t; idx < 5120; idx += 256){
    int i = idx >> 7, p = idx & 127;
    float acc = 0.f;
    #pragma unroll 8
    for (int m = 0; m < 40; ++m) acc = fmaf(As[i * 40 + m], xf[p * 41 + m], acc);
    M[i * 128 + p] = acc;
  }
  __syncthreads();
  float* dst = H + (size_t)b * (N * HG);
  for (int idx = t; idx < 5120; idx += 256){
    int i = idx >> 7, j = idx & 127;
    float acc = bias[j];
    for (int p = 0; p < 128; ++p) acc = fmaf(M[i * 128 + p], w[p * 128 + j], acc);
    dst[i * 128 + j] = (acc >= 0.f) ? acc : 0.01f * acc;
  }
}

// ---------- K6: H_t ----------
__global__ __launch_bounds__(256) void ht_kernel(const float* __restrict__ Xf,
    const float* __restrict__ At_g, const float* __restrict__ w, const float* __restrict__ bias,
    float* __restrict__ H){
  const int b = blockIdx.x, t = threadIdx.x;
  __shared__ float xf[128 * 41];
  __shared__ float M2[128 * 40];
  const float* src = Xf + b * 5120;
  for (int idx = t; idx < 5120; idx += 256){ int p = idx / 40, c = idx - p * 40; xf[p * 41 + c] = src[idx]; }
  __syncthreads();
  const float* At = At_g + (size_t)b * 16384;
  for (int idx = t; idx < 5120; idx += 256){
    int i = idx / 40, c = idx - i * 40;
    float acc = 0.f;
    for (int m = 0; m < 128; ++m) acc = fmaf(At[i * 128 + m], xf[m * 41 + c], acc);
    M2[i * 40 + c] = acc;
  }
  __syncthreads();
  float* dst = H + (size_t)b * (N * HG) + 40 * 128;
  for (int idx = t; idx < 16384; idx += 256){
    int i = idx >> 7, j = idx & 127;
    float acc = bias[j];
    #pragma unroll 8
    for (int c = 0; c < 40; ++c) acc = fmaf(M2[i * 40 + c], w[c * 128 + j], acc);
    dst[i * 128 + j] = (acc >= 0.f) ? acc : 0.01f * acc;
  }
}

__global__ void initout_kernel(float* __restrict__ out, const float* __restrict__ fcb){
  int i = blockIdx.x * 256 + threadIdx.x;
  if (i < BSZ) out[i] = fcb[0];
}

// ---------- prep: per-head M^T, Wv^T, c1/c2/c3; sliced over 8 blocks/head ----------
__global__ __launch_bounds__(256) void prep_kernel(
    const float* __restrict__ qw, const float* __restrict__ qb,
    const float* __restrict__ kw, const float* __restrict__ kb,
    const float* __restrict__ vw,
    short* __restrict__ MT, short* __restrict__ WvT,
    float* __restrict__ c1, float* __restrict__ c2, float* __restrict__ c3){
  const int h = blockIdx.x, sl = blockIdx.y, t = threadIdx.x;
  const float* Q = qw + h * 16384;
  const float* K = kw + h * 16384;
  const float* V = vw + h * 16384;
  for (int idx = t; idx < 2048; idx += 256){
    int j = sl * 16 + (idx >> 7), d = idx & 127;
    float acc = 0.f;
    for (int e = 0; e < 128; ++e) acc = fmaf(Q[d * 128 + e], K[j * 128 + e], acc);
    MT[h * 16384 + j * 128 + d] = (short)f2bf(acc);     // MT[j][d] = M[d][j]
  }
  for (int idx = t; idx < 2048; idx += 256){
    int e = sl * 16 + (idx >> 7), d = idx & 127;
    WvT[h * 16384 + e * 128 + d] = (short)f2bf(V[d * 128 + e]);
  }
  if (t < 16){
    int r = sl * 16 + t;
    float a = 0.f, bsum = 0.f;
    for (int e = 0; e < 128; ++e){
      a    = fmaf(Q[r * 128 + e], kb[h * 128 + e], a);
      bsum = fmaf(K[r * 128 + e], qb[h * 128 + e], bsum);
    }
    c1[h * 128 + r] = a;
    c2[h * 128 + r] = bsum;
  }
  if (t == 16 && sl == 0){
    float a = 0.f;
    for (int e = 0; e < 128; ++e) a = fmaf(qb[h * 128 + e], kb[h * 128 + e], a);
    c3[h] = a;
  }
}

// ---------- cast H -> bf16 with zero-padded rows 168..175 ----------
__global__ __launch_bounds__(256) void cast_kernel(const float* __restrict__ H,
                                                   short* __restrict__ Hbf){
  const int b = blockIdx.x;
  for (int idx = threadIdx.x; idx < NPAD * 128; idx += 256){
    int n = idx >> 7, d = idx & 127;
    float v = (n < N) ? H[((size_t)b * N + n) * 128 + d] : 0.f;
    Hbf[(size_t)b * NPAD * 128 + idx] = (short)f2bf(v);
  }
}

// ---------- transpose Hbf -> HbT [e][m], m padded to 192 with zeros ----------
__global__ __launch_bounds__(256) void castT_kernel(const short* __restrict__ Hbf,
                                                    short* __restrict__ HbT){
  const int b = blockIdx.x;
  __shared__ short tile[176 * 130];
  const short* src = Hbf + (size_t)b * NPAD * 128;
  for (int idx = threadIdx.x; idx < 176 * 128; idx += 256){
    int m = idx >> 7, e = idx & 127;
    tile[m * 130 + e] = src[idx];
  }
  __syncthreads();
  short* dst = HbT + (size_t)b * 128 * 192;
  for (int idx = threadIdx.x; idx < 128 * 192; idx += 256){
    int e = idx / 192, m = idx - e * 192;
    dst[idx] = (m < 176) ? tile[m * 130 + e] : (short)0;
  }
}

// ---------- u1/u2 precompute: u1[n]=H[n]·c1, u2[n]=H[n]·c2 per (b,h) ----------
__global__ __launch_bounds__(256) void uprep_kernel(const short* __restrict__ Hbf,
    const float* __restrict__ c1, const float* __restrict__ c2,
    float* __restrict__ u1g, float* __restrict__ u2g){
  const int b = blockIdx.x, t = threadIdx.x;
  for (int idx = t; idx < 176 * 4; idx += 256){
    int n = idx >> 2, h = idx & 3;
    const bf16x8* rp = (const bf16x8*)(Hbf + (size_t)b * NPAD * 128 + (size_t)n * 128);
    const float* C1 = c1 + h * 128;
    const float* C2 = c2 + h * 128;
    float a1 = 0.f, a2 = 0.f;
    for (int kk = 0; kk < 16; ++kk){
      bf16x8 v = rp[kk];
      #pragma unroll
      for (int j = 0; j < 8; ++j){
        float hv = bf2f((unsigned short)v[j]);
        a1 = fmaf(hv, C1[kk * 8 + j], a1);
        a2 = fmaf(hv, C2[kk * 8 + j], a2);
      }
    }
    u1g[(size_t)(b * 4 + h) * 176 + n] = a1;
    u2g[(size_t)(b * 4 + h) * 176 + n] = a2;
  }
}

// ---------- attention mega-kernel: grid (b, h, z), z=0..3 row chunks ----------
__global__ __launch_bounds__(256) void attn_mega(
    const short* __restrict__ Hbf, const short* __restrict__ HbT,
    const short* __restrict__ MT, const short* __restrict__ WvT,
    const float* __restrict__ u1g, const float* __restrict__ u2g,
    const float* __restrict__ c3g, const float* __restrict__ vb,
    const float* __restrict__ fcw, float* __restrict__ out){
  const int b = blockIdx.x, h = blockIdx.y, z = blockIdx.z;
  const int NT = (z < 3) ? 3 : 2;
  const int rows = NT * 16;
  const int rowbase = z * 48;
  const int t = threadIdx.x;
  const int w = t >> 6, l = t & 63, quad = l >> 4, l15 = l & 15;

  __shared__ __align__(16) short Tsh[48 * 128];       // T then stats then U
  __shared__ __align__(16) short Ssh[48 * 184 + 16];  // S then P (bf16, stride 184)
  __shared__ float u1s[48];
  __shared__ float u2s[176];
  __shared__ float red4[4];

  const short* Hb   = Hbf + (size_t)b * NPAD * 128;
  const short* HT   = HbT + (size_t)b * 128 * 192;
  const short* MTh  = MT + h * 16384;
  const short* WvTh = WvT + h * 16384;
  const float c3v = c3g[h];
  const float inv = 0.08838834764831845f;   // 1/sqrt(128)

  if (t < 176) u2s[t] = u2g[(size_t)(b * 4 + h) * 176 + t];
  if (t < rows) u1s[t] = u1g[(size_t)(b * 4 + h) * 176 + rowbase + t];

  // ---- Phase A: T = H_rows @ M  (write bf16, XOR-swizzled) ----
  for (int jt = 0; jt < 2; ++jt){
    const int j0 = (w * 2 + jt) * 16;
    bf16x8 B[4];
    #pragma unroll
    for (int kk = 0; kk < 4; ++kk)
      B[kk] = *(const bf16x8*)(MTh + (j0 + l15) * 128 + kk * 32 + quad * 8);
    for (int nt = 0; nt < NT; ++nt){
      f32x4 acc = {0.f, 0.f, 0.f, 0.f};
      #pragma unroll
      for (int kk = 0; kk < 4; ++kk){
        bf16x8 A = *(const bf16x8*)(Hb + (size_t)(rowbase + nt * 16 + l15) * 128 + kk * 32 + quad * 8);
        acc = __builtin_amdgcn_mfma_f32_16x16x32_bf16(A, B[kk], acc, 0, 0, 0);
      }
      const int jcol = j0 + l15, ch = jcol >> 3;
      #pragma unroll
      for (int r = 0; r < 4; ++r){
        int row = nt * 16 + quad * 4 + r;
        Tsh[row * 128 + ((ch ^ (row & 15)) << 3) + (jcol & 7)] = (short)f2bf(acc[r]);
      }
    }
  }
  __syncthreads();

  // ---- Phase B: S = T @ H^T (+rank-1 terms), bf16 into Ssh ----
  for (int mi = 0; mi < 3; ++mi){
    const int mt = w + mi * 4;
    if (mt >= 11) break;
    const int m0 = mt * 16;
    bf16x8 B[4];
    #pragma unroll
    for (int kk = 0; kk < 4; ++kk)
      B[kk] = *(const bf16x8*)(Hb + (size_t)(m0 + l15) * 128 + kk * 32 + quad * 8);
    const int m = m0 + l15;
    const float u2v = u2s[m];
    for (int nt = 0; nt < NT; ++nt){
      f32x4 acc = {0.f, 0.f, 0.f, 0.f};
      #pragma unroll
      for (int kk = 0; kk < 4; ++kk){
        int row = nt * 16 + l15;
        bf16x8 A = *(const bf16x8*)(&Tsh[row * 128 + (((kk * 4 + quad) ^ l15) << 3)]);
        acc = __builtin_amdgcn_mfma_f32_16x16x32_bf16(A, B[kk], acc, 0, 0, 0);
      }
      #pragma unroll
      for (int r = 0; r < 4; ++r){
        int nl = nt * 16 + quad * 4 + r;
        float s = (acc[r] + u1s[nl] + u2v + c3v) * inv;
        Ssh[nl * 184 + m] = (short)f2bf(s);
      }
    }
  }
  __syncthreads();

  // ---- softmax over valid cols m<168; write P bf16 (cols 168..175 = 0) ----
  {
    float* rstat = (float*)Tsh;      // T data dead
    float* mxh  = rstat;             // [96]
    float* smh  = rstat + 96;        // [96]
    float* mxf  = rstat + 192;       // [48]
    float* sinv = rstat + 240;       // [48]
    if (t < 2 * rows){
      int r = t >> 1, hh = t & 1;
      const short* rowp = &Ssh[r * 184 + hh * 84];
      float mv = -1e30f;
      for (int m2 = 0; m2 < 84; ++m2) mv = fmaxf(mv, bf2f((unsigned short)rowp[m2]));
      mxh[t] = mv;
    }
    __syncthreads();
    if (t < rows) mxf[t] = fmaxf(mxh[2 * t], mxh[2 * t + 1]);
    __syncthreads();
    if (t < 2 * rows){
      int r = t >> 1, hh = t & 1;
      const short* rowp = &Ssh[r * 184 + hh * 84];
      float mv = mxf[r], sm = 0.f;
      for (int m2 = 0; m2 < 84; ++m2) sm += expf(bf2f((unsigned short)rowp[m2]) - mv);
      smh[t] = sm;
    }
    __syncthreads();
    if (t < rows) sinv[t] = 1.f / (smh[2 * t] + smh[2 * t + 1]);
    __syncthreads();
    for (int idx = t; idx < rows * 176; idx += 256){
      int r = idx / 176, m2 = idx - r * 176;
      short val = 0;
      if (m2 < 168){
        float s = bf2f((unsigned short)Ssh[r * 184 + m2]);
        val = (short)f2bf(expf(s - mxf[r]) * sinv[r]);
      }
      Ssh[r * 184 + m2] = val;
    }
  }
  __syncthreads();

  // ---- Phase C: U = P @ H  (B from transposed HbT; write U into Tsh swizzled) ----
  for (int ei = 0; ei < 2; ++ei){
    const int e0 = (w * 2 + ei) * 16;
    bf16x8 B[6];
    #pragma unroll
    for (int kt = 0; kt < 6; ++kt)
      B[kt] = *(const bf16x8*)(HT + (size_t)(e0 + l15) * 192 + kt * 32 + quad * 8);
    for (int nt = 0; nt < NT; ++nt){
      f32x4 acc = {0.f, 0.f, 0.f, 0.f};
      #pragma unroll
      for (int kt = 0; kt < 6; ++kt){
        bf16x8 A = {0, 0, 0, 0, 0, 0, 0, 0};
        if (kt != 5 || quad < 2)
          A = *(const bf16x8*)(&Ssh[(nt * 16 + l15) * 184 + kt * 32 + quad * 8]);
        acc = __builtin_amdgcn_mfma_f32_16x16x32_bf16(A, B[kt], acc, 0, 0, 0);
      }
      const int ecol = e0 + l15, ch = ecol >> 3;
      #pragma unroll
      for (int r = 0; r < 4; ++r){
        int row = nt * 16 + quad * 4 + r;
        Tsh[row * 128 + ((ch ^ (row & 15)) << 3) + (ecol & 7)] = (short)f2bf(acc[r]);
      }
    }
  }
  __syncthreads();

  // ---- Phase D: O = U @ Wv + vb, fused FC reduction ----
  float tp = 0.f;
  for (int ei = 0; ei < 2; ++ei){
    const int e0 = (w * 2 + ei) * 16;
    bf16x8 B[4];
    #pragma unroll
    for (int kk = 0; kk < 4; ++kk)
      B[kk] = *(const bf16x8*)(WvTh + (e0 + l15) * 128 + kk * 32 + quad * 8);
    const float vbv = vb[h * 128 + e0 + l15];
    for (int nt = 0; nt < NT; ++nt){
      f32x4 acc = {0.f, 0.f, 0.f, 0.f};
      #pragma unroll
      for (int kk = 0; kk < 4; ++kk){
        int row = nt * 16 + l15;
        bf16x8 A = *(const bf16x8*)(&Tsh[row * 128 + (((kk * 4 + quad) ^ l15) << 3)]);
        acc = __builtin_amdgcn_mfma_f32_16x16x32_bf16(A, B[kk], acc, 0, 0, 0);
      }
      #pragma unroll
      for (int r = 0; r < 4; ++r){
        int ng = rowbase + nt * 16 + quad * 4 + r;
        if (ng < N)
          tp = fmaf(acc[r] + vbv, fcw[ng * 512 + h * 128 + e0 + l15], tp);
      }
    }
  }
  float tot = rsum256(tp, red4);
  if (t == 0) atomicAdd(out + b, tot);
}

} // anonymous namespace

extern "C" void kernel_launch(void* const* d_in, const int* in_sizes, int n_in,
                              void* d_out, int out_size, void* d_ws, size_t ws_size,
                              hipStream_t stream) {
  (void)in_sizes; (void)n_in; (void)out_size;
  const float* X      = (const float*)d_in[0];
  const float* spa_w1 = (const float*)d_in[1];
  const float* spa_b1 = (const float*)d_in[2];
  const float* spa_w2 = (const float*)d_in[3];
  const float* spa_b2 = (const float*)d_in[4];
  const float* tem_w1 = (const float*)d_in[5];
  const float* tem_b1 = (const float*)d_in[6];
  const float* tem_w2 = (const float*)d_in[7];
  const float* tem_b2 = (const float*)d_in[8];
  const float* sgnn_w = (const float*)d_in[9];
  const float* sgnn_b = (const float*)d_in[10];
  const float* tgnn_w = (const float*)d_in[11];
  const float* tgnn_b = (const float*)d_in[12];
  const float* q_w    = (const float*)d_in[13];
  const float* q_b    = (const float*)d_in[14];
  const float* k_w    = (const float*)d_in[15];
  const float* k_b    = (const float*)d_in[16];
  const float* v_w    = (const float*)d_in[17];
  const float* v_b    = (const float*)d_in[18];
  const float* fc_w   = (const float*)d_in[19];
  const float* fc_b   = (const float*)d_in[20];
  float* out = (float*)d_out;

  // ws layout (bytes):
  //   [0, 88,080,384): H fp32 (phase1) -> dead after cast; then:
  //       HbT bf16 1024x128x192   @ 0          (50,331,648)
  //       u1g fp32 1024x4x176     @ 50,331,648 (2,883,584)
  //       u2g fp32 1024x4x176     @ 53,215,232 (2,883,584)
  //   Rb = 88,080,384:
  //       phase1: Xf (20,971,520) | As (6,553,600) | At (67,108,864; ends at ws end)
  //       phase2: Hbf bf16 1024x176x128 @ Rb (46,137,344)
  //               prep @ Rb+46,137,344 (inside dead At): MT|WvT|c1|c2|c3
  if (ws_size < (size_t)182714368) return;

  char* wsb = (char*)d_ws;
  float* H   = (float*)wsb;
  short* HbT = (short*)wsb;
  float* u1g = (float*)(wsb + 50331648);
  float* u2g = (float*)(wsb + 53215232);
  char*  Rb  = wsb + 88080384;
  float* Xf  = (float*)Rb;
  float* As  = (float*)(Rb + 20971520);
  float* At  = (float*)(Rb + 27525120);
  short* Hbf = (short*)Rb;
  char*  Pb  = Rb + 46137344;
  short* MT  = (short*)Pb;
  short* WvT = (short*)(Pb + 131072);
  float* c1  = (float*)(Pb + 262144);
  float* c2  = (float*)(Pb + 264192);
  float* c3  = (float*)(Pb + 266240);

  feat_kernel<<<BSZ * P / 4, 256, 0, stream>>>(X, Xf);
  cumnorm_kernel<<<BSZ, 256, 0, stream>>>(Xf);
  adjt_kernel<<<BSZ, 256, 0, stream>>>(Xf, tem_w1, tem_b1, tem_w2, tem_b2, At);
  adjs_kernel<<<BSZ, 256, 0, stream>>>(Xf, spa_w1, spa_b1, spa_w2, spa_b2, As);
  hs_kernel<<<BSZ, 256, 0, stream>>>(Xf, As, sgnn_w, sgnn_b, H);
  ht_kernel<<<BSZ, 256, 0, stream>>>(Xf, At, tgnn_w, tgnn_b, H);
  prep_kernel<<<dim3(NH, 8), 256, 0, stream>>>(q_w, q_b, k_w, k_b, v_w, MT, WvT, c1, c2, c3);
  cast_kernel<<<BSZ, 256, 0, stream>>>(H, Hbf);          // H fp32 dead after this
  castT_kernel<<<BSZ, 256, 0, stream>>>(Hbf, HbT);       // writes into dead-H region
  uprep_kernel<<<BSZ, 256, 0, stream>>>(Hbf, c1, c2, u1g, u2g);
  initout_kernel<<<4, 256, 0, stream>>>(out, fc_b);
  attn_mega<<<dim3(BSZ, NH, 4), 256, 0, stream>>>(Hbf, HbT, MT, WvT, u1g, u2g, c3, v_b, fc_w, out);
}

// Round 5
// 1357.296 us; speedup vs baseline: 5.9675x; 1.3030x over previous
//
#include <hip/hip_runtime.h>
#include <math.h>

namespace {

constexpr int BSZ  = 1024;
constexpr int P    = 128;
constexpr int HG   = 128;
constexpr int NH   = 4;
constexpr int N    = 168;     // P + IND
constexpr int NPAD = 176;     // padded token count (11 tiles of 16)

typedef short bf16x8 __attribute__((ext_vector_type(8)));
typedef float f32x4  __attribute__((ext_vector_type(4)));

__device__ __forceinline__ unsigned short f2bf(float x){
  union { float f; unsigned u; } v; v.f = x;
  unsigned r = (v.u + 0x7FFF + ((v.u >> 16) & 1)) >> 16;
  return (unsigned short)r;
}
__device__ __forceinline__ float bf2f(unsigned short b){
  union { unsigned u; float f; } v; v.u = ((unsigned)b) << 16;
  return v.f;
}

// ---------- wave (64-lane) butterfly reductions: result in ALL lanes ----------
__device__ __forceinline__ float wsum(float v){
  #pragma unroll
  for (int o = 1; o < 64; o <<= 1) v += __shfl_xor(v, o, 64);
  return v;
}
__device__ __forceinline__ float wmax(float v){
  #pragma unroll
  for (int o = 1; o < 64; o <<= 1) v = fmaxf(v, __shfl_xor(v, o, 64));
  return v;
}
__device__ __forceinline__ float wmin(float v){
  #pragma unroll
  for (int o = 1; o < 64; o <<= 1) v = fminf(v, __shfl_xor(v, o, 64));
  return v;
}
__device__ __forceinline__ float rsum256(float v, volatile float* red4){
  #pragma unroll
  for (int o = 32; o > 0; o >>= 1) v += __shfl_down(v, o, 64);
  __syncthreads();
  if ((threadIdx.x & 63) == 0) red4[threadIdx.x >> 6] = v;
  __syncthreads();
  return red4[0] + red4[1] + red4[2] + red4[3];
}

// ---------- K1: per-patch features, one WAVE per patch, no LDS, no barriers ----------
__global__ __launch_bounds__(256) void feat_kernel(const float* __restrict__ X,
                                                   float* __restrict__ Xf){
  const int wave = threadIdx.x >> 6, l = threadIdx.x & 63;
  const int pp = blockIdx.x * 4 + wave;          // patch id
  const float* xp = X + (size_t)pp * 128;
  const float x0 = xp[l];
  const float x1 = xp[l + 64];

  // ---- temporal ----
  float sum   = wsum(x0 + x1);
  float mean  = sum * (1.0f / 128.0f);
  float mx    = wmax(fmaxf(x0, x1));
  float mn    = wmin(fminf(x0, x1));
  float sumsq = wsum(fmaf(x0, x0, x1 * x1));
  float c0 = x0 - mean, c1_ = x1 - mean;
  float c0q = c0 * c0, c1q = c1_ * c1_;
  float m2 = wsum(c0q + c1q);
  float m3 = wsum(c0q * c0 + c1q * c1_);
  float m4 = wsum(c0q * c0q + c1q * c1q);
  float var = m2 * (1.0f / 127.0f);
  float sd  = sqrtf(var);
  float rms = sqrtf(sumsq * (1.0f / 128.0f));
  float ex0 = expf(x0 - mx), ex1 = expf(x1 - mx);
  float Z   = wsum(ex0 + ex1);
  float SxE = wsum(fmaf(ex0, x0, ex1 * x1));
  float ent = (mx + logf(Z)) - SxE / Z;
  const float lo = (float)(-1.0 + 1e-7), hi = (float)(1.0 - 1e-7);
  float a0 = asinf(fminf(fmaxf(x0, lo), hi));
  float a1 = asinf(fminf(fmaxf(x1, lo), hi));
  float amean = wsum(a0 + a1) * (1.0f / 128.0f);
  float ad0 = a0 - amean, ad1 = a1 - amean;
  float std_asin = sqrtf(wsum(fmaf(ad0, ad0, ad1 * ad1)) * (1.0f / 127.0f));
  float b0 = atanf(x0), b1v = atanf(x1);
  float bmean = wsum(b0 + b1v) * (1.0f / 128.0f);
  float bd0 = b0 - bmean, bd1 = b1v - bmean;
  float std_atan = sqrtf(wsum(fmaf(bd0, bd0, bd1 * bd1)) * (1.0f / 127.0f));
  float kurt = (m4 * (1.0f / 128.0f)) / (sd * sd * sd * sd) - 3.0f;
  float skew = (m3 * (1.0f / 128.0f)) / (sd * sd * sd);

  // ---- DFT: lane l computes bin l via rotation recurrence (64 folded steps) ----
  const float sign = (l & 1) ? -1.0f : 1.0f;
  float sC, cC;
  __sincosf((float)l * 0.049087385212340517f, &sC, &cC);   // 2*pi*l/128
  const float c1r = cC, s1r = -sC;
  const int x0i = __float_as_int(x0), x1i = __float_as_int(x1);
  float re = 0.f, im = 0.f;
  float wc = 1.f, ws = 0.f;
  #pragma unroll 8
  for (int tt = 0; tt < 32; ++tt){
    float s0v = __int_as_float(__builtin_amdgcn_readlane(x0i, tt));
    float s1v = __int_as_float(__builtin_amdgcn_readlane(x1i, tt));
    float se = fmaf(sign, s1v, s0v);
    re = fmaf(se, wc, re);
    im = fmaf(se, ws, im);
    float t1 = ws * s1r, t2 = ws * c1r;
    float nwc = fmaf(wc, c1r, -t1);
    ws = fmaf(wc, s1r, t2);
    wc = nwc;
  }
  { // exact reseed at tt=32: w = e^{-i*pi*l/2}
    int lm = l & 3;
    wc = (lm == 0) ? 1.f : (lm == 2) ? -1.f : 0.f;
    ws = (lm == 1) ? -1.f : (lm == 3) ? 1.f : 0.f;
  }
  #pragma unroll 8
  for (int tt = 32; tt < 64; ++tt){
    float s0v = __int_as_float(__builtin_amdgcn_readlane(x0i, tt));
    float s1v = __int_as_float(__builtin_amdgcn_readlane(x1i, tt));
    float se = fmaf(sign, s1v, s0v);
    re = fmaf(se, wc, re);
    im = fmaf(se, ws, im);
    float t1 = ws * s1r, t2 = ws * c1r;
    float nwc = fmaf(wc, c1r, -t1);
    ws = fmaf(wc, s1r, t2);
    wc = nwc;
  }
  float psd = fmaf(re, re, im * im) * 0.0078125f;          // bins 0..63 (lane l)
  float re64 = wsum(sign * (x0 + x1));                     // bin 64
  float psd64 = re64 * re64 * 0.0078125f;

  const float mult = (l == 0) ? 1.f : 2.f;
  float psum = wsum(psd * mult) + psd64;
  float p2   = wsum(psd * psd * mult) + psd64 * psd64;
  float vm   = wmax(psd);
  float maxp = fmaxf(vm, psd64);
  float meanfreq = (-0.5f * psd64) / psum;
  float pbw = sqrtf(p2 / psum);
  float cand = (psd == vm) ? (float)l : 1e9f;              // first-index argmax
  float lminf = wmin(cand);
  float fmaxv = (psd64 > vm) ? -0.5f : lminf * (1.0f / 128.0f);
  float maxamp = sqrtf(maxp * 128.0f);

  // ---- median (stable rank 64 of 128, multiplicity-aware ballot rank) ----
  float med = -0.5f;
  for (int kt = 0; kt < 64; ++kt){
    float vt = __int_as_float(__builtin_amdgcn_readlane(__float_as_int(psd), kt));
    unsigned long long mask = __ballot(psd < vt);
    int less = 2 * __popcll(mask) - (int)(mask & 1ull) + ((psd64 < vt) ? 1 : 0);
    if (less == 64) med = (float)kt * (1.0f / 128.0f);
    else if (less == 63 && kt >= 1) med = -(float)kt * (1.0f / 128.0f);
  }
  {
    unsigned long long mask = __ballot(psd < psd64);
    int less = 2 * __popcll(mask) - (int)(mask & 1ull);
    if (less == 64) med = -0.5f;
  }

  if (l == 0){
    float* o = Xf + (size_t)pp * 40;
    o[0]  = mx;  o[1]  = mn;  o[2]  = sd;   o[3]  = rms; o[4]  = mean;
    o[5]  = mx - mn;  o[6] = var;  o[7] = ent; o[8] = std_asin; o[9] = std_atan;
    o[10] = kurt; o[11] = skew;
    o[12] = meanfreq;
    o[13] = med;
    o[14] = psum;
    o[15] = 1.0f;
    o[16] = pbw;
    o[17] = maxp;
    o[18] = maxamp;
    o[19] = fmaxv;
  }
}

// ---------- K2: cumsum feature + per-sample normalization ----------
__global__ __launch_bounds__(256) void cumnorm_kernel(float* __restrict__ Xf){
  const int b = blockIdx.x, t = threadIdx.x;
  __shared__ float arr[128 * 40];
  __shared__ float red4[4];
  float* base = Xf + b * 5120;
  for (int idx = t; idx < 128 * 20; idx += 256){
    int p = idx / 20, c = idx - p * 20;
    arr[p * 40 + c] = base[p * 40 + c];
  }
  __syncthreads();
  if (t < 20){
    float acc = 0.f;
    for (int p = 0; p < 128; ++p){
      acc += arr[p * 40 + t];
      arr[p * 40 + 20 + t] = acc / sqrtf(fmaxf(fabsf(acc), 1e-12f));
    }
  }
  __syncthreads();
  float pa = 0.f;
  for (int idx = t; idx < 5120; idx += 256){ float v = arr[idx]; pa = fmaf(v, v, pa); }
  float nrm = sqrtf(rsum256(pa, red4));
  for (int idx = t; idx < 5120; idx += 256) base[idx] = arr[idx] / nrm;
}

// ---------- K3: A_t (register-tiled fp32; K-order per output unchanged) ----------
__global__ __launch_bounds__(256) void adjt_kernel(const float* __restrict__ Xf,
    const float* __restrict__ w1, const float* __restrict__ b1,
    const float* __restrict__ w2, const float* __restrict__ b2,
    float* __restrict__ At){
  const int b = blockIdx.x, t = threadIdx.x;
  __shared__ float xf[5120];          // stride 40
  __shared__ float T[128 * 64];
  const float* src = Xf + b * 5120;
  for (int idx = t; idx < 1280; idx += 256)
    *((float4*)xf + idx) = *((const float4*)src + idx);
  __syncthreads();

  // T1[i][k] = tanh(b1[k] + sum_c xf[i][c]*w1[c][k]); tile 8i x 4k per thread
  {
    const int k0 = (t & 15) * 4, i0 = (t >> 4) * 8;
    float4 bv = *(const float4*)&b1[k0];
    float acc[8][4];
    #pragma unroll
    for (int di = 0; di < 8; ++di){ acc[di][0]=bv.x; acc[di][1]=bv.y; acc[di][2]=bv.z; acc[di][3]=bv.w; }
    for (int c = 0; c < 40; ++c){
      float4 wv = *(const float4*)&w1[c * 64 + k0];
      #pragma unroll
      for (int di = 0; di < 8; ++di){
        float xv = xf[(i0 + di) * 40 + c];
        acc[di][0] = fmaf(xv, wv.x, acc[di][0]);
        acc[di][1] = fmaf(xv, wv.y, acc[di][1]);
        acc[di][2] = fmaf(xv, wv.z, acc[di][2]);
        acc[di][3] = fmaf(xv, wv.w, acc[di][3]);
      }
    }
    #pragma unroll
    for (int di = 0; di < 8; ++di){
      float4 o;
      o.x = tanhf(acc[di][0]); o.y = tanhf(acc[di][1]);
      o.z = tanhf(acc[di][2]); o.w = tanhf(acc[di][3]);
      *(float4*)&T[(i0 + di) * 64 + k0] = o;
    }
  }
  __syncthreads();

  // A_t[i][j] = b2[j] + sum_k T[i][k]*w2[k][j]; tile 16i x 4j per thread
  {
    const int j0 = (t & 31) * 4, i0 = (t >> 5) * 16;
    float4 bv = *(const float4*)&b2[j0];
    float acc[16][4];
    #pragma unroll
    for (int di = 0; di < 16; ++di){ acc[di][0]=bv.x; acc[di][1]=bv.y; acc[di][2]=bv.z; acc[di][3]=bv.w; }
    for (int k = 0; k < 64; ++k){
      float4 wv = *(const float4*)&w2[k * 128 + j0];
      #pragma unroll
      for (int di = 0; di < 16; ++di){
        float tv = T[(i0 + di) * 64 + k];
        acc[di][0] = fmaf(tv, wv.x, acc[di][0]);
        acc[di][1] = fmaf(tv, wv.y, acc[di][1]);
        acc[di][2] = fmaf(tv, wv.z, acc[di][2]);
        acc[di][3] = fmaf(tv, wv.w, acc[di][3]);
      }
    }
    float* dst = At + (size_t)b * 16384;
    #pragma unroll
    for (int di = 0; di < 16; ++di)
      *(float4*)&dst[(i0 + di) * 128 + j0] = *(float4*)acc[di];
  }
}

// ---------- K4: A_s ----------
__global__ __launch_bounds__(256) void adjs_kernel(const float* __restrict__ Xf,
    const float* __restrict__ w1, const float* __restrict__ b1,
    const float* __restrict__ w2, const float* __restrict__ b2,
    float* __restrict__ As){
  const int b = blockIdx.x, t = threadIdx.x;
  __shared__ float xf[5120];
  __shared__ float T2[40 * 64];
  const float* src = Xf + b * 5120;
  for (int idx = t; idx < 1280; idx += 256)
    *((float4*)xf + idx) = *((const float4*)src + idx);
  __syncthreads();
  for (int idx = t; idx < 40 * 64; idx += 256){
    int i = idx >> 6, k = idx & 63;
    float acc = b1[k];
    for (int p = 0; p < 128; ++p) acc = fmaf(xf[p * 40 + i], w1[p * 64 + k], acc);
    T2[idx] = tanhf(acc);
  }
  __syncthreads();
  float* dst = As + b * 1600;
  for (int idx = t; idx < 1600; idx += 256){
    int i = idx / 40, j = idx - i * 40;
    float acc = b2[j];
    #pragma unroll 8
    for (int k = 0; k < 64; ++k) acc = fmaf(T2[i * 64 + k], w2[k * 40 + j], acc);
    dst[idx] = acc;
  }
}

// ---------- K5: H_s (register-tiled) ----------
__global__ __launch_bounds__(256) void hs_kernel(const float* __restrict__ Xf,
    const float* __restrict__ As_g, const float* __restrict__ w, const float* __restrict__ bias,
    float* __restrict__ H){
  const int b = blockIdx.x, t = threadIdx.x;
  __shared__ float xf[5120];          // stride 40
  __shared__ float As[1600];
  __shared__ float M[40 * 128];
  const float* src = Xf + b * 5120;
  for (int idx = t; idx < 1280; idx += 256)
    *((float4*)xf + idx) = *((const float4*)src + idx);
  for (int idx = t; idx < 400; idx += 256)
    *((float4*)As + idx) = *((const float4*)(As_g + b * 1600) + idx);
  __syncthreads();

  // M[i][p] = sum_m As[i][m] * xf[p][m]; tile 5i x 4p, m in float4 steps
  {
    const int p0 = (t & 31) * 4, i0 = (t >> 5) * 5;
    float acc[5][4];
    #pragma unroll
    for (int di = 0; di < 5; ++di)
      #pragma unroll
      for (int dp = 0; dp < 4; ++dp) acc[di][dp] = 0.f;
    for (int m = 0; m < 40; m += 4){
      float4 a4[5], x4[4];
      #pragma unroll
      for (int di = 0; di < 5; ++di) a4[di] = *(const float4*)&As[(i0 + di) * 40 + m];
      #pragma unroll
      for (int dp = 0; dp < 4; ++dp) x4[dp] = *(const float4*)&xf[(p0 + dp) * 40 + m];
      #pragma unroll
      for (int dm = 0; dm < 4; ++dm)
        #pragma unroll
        for (int di = 0; di < 5; ++di){
          float av = (&a4[di].x)[dm];
          #pragma unroll
          for (int dp = 0; dp < 4; ++dp)
            acc[di][dp] = fmaf(av, (&x4[dp].x)[dm], acc[di][dp]);
        }
    }
    #pragma unroll
    for (int di = 0; di < 5; ++di)
      *(float4*)&M[(i0 + di) * 128 + p0] = *(float4*)acc[di];
  }
  __syncthreads();

  // H_s[i][j] = leaky(bias[j] + sum_p M[i][p]*w[p][j]); tile 5i x 4j
  {
    const int j0 = (t & 31) * 4, i0 = (t >> 5) * 5;
    float4 bv = *(const float4*)&bias[j0];
    float acc[5][4];
    #pragma unroll
    for (int di = 0; di < 5; ++di){ acc[di][0]=bv.x; acc[di][1]=bv.y; acc[di][2]=bv.z; acc[di][3]=bv.w; }
    for (int p = 0; p < 128; ++p){
      float4 wv = *(const float4*)&w[p * 128 + j0];
      #pragma unroll
      for (int di = 0; di < 5; ++di){
        float mv = M[(i0 + di) * 128 + p];
        acc[di][0] = fmaf(mv, wv.x, acc[di][0]);
        acc[di][1] = fmaf(mv, wv.y, acc[di][1]);
        acc[di][2] = fmaf(mv, wv.z, acc[di][2]);
        acc[di][3] = fmaf(mv, wv.w, acc[di][3]);
      }
    }
    float* dst = H + (size_t)b * (N * HG);
    #pragma unroll
    for (int di = 0; di < 5; ++di){
      float4 o;
      o.x = (acc[di][0] >= 0.f) ? acc[di][0] : 0.01f * acc[di][0];
      o.y = (acc[di][1] >= 0.f) ? acc[di][1] : 0.01f * acc[di][1];
      o.z = (acc[di][2] >= 0.f) ? acc[di][2] : 0.01f * acc[di][2];
      o.w = (acc[di][3] >= 0.f) ? acc[di][3] : 0.01f * acc[di][3];
      *(float4*)&dst[(i0 + di) * 128 + j0] = o;
    }
  }
}

// ---------- K6: H_t (register-tiled) ----------
__global__ __launch_bounds__(256) void ht_kernel(const float* __restrict__ Xf,
    const float* __restrict__ At_g, const float* __restrict__ w, const float* __restrict__ bias,
    float* __restrict__ H){
  const int b = blockIdx.x, t = threadIdx.x;
  __shared__ float xf[5120];          // stride 40
  __shared__ float M2[128 * 40];
  const float* src = Xf + b * 5120;
  for (int idx = t; idx < 1280; idx += 256)
    *((float4*)xf + idx) = *((const float4*)src + idx);
  __syncthreads();

  // M2[i][c] = sum_m At[i][m] * xf[m][c]; tile 4i x 5c, m in float4 steps
  {
    const int c0 = (t & 7) * 5, i0 = (t >> 3) * 4;
    const float* At = At_g + (size_t)b * 16384;
    float acc[4][5];
    #pragma unroll
    for (int di = 0; di < 4; ++di)
      #pragma unroll
      for (int dc = 0; dc < 5; ++dc) acc[di][dc] = 0.f;
    for (int m = 0; m < 128; m += 4){
      float4 a4[4];
      #pragma unroll
      for (int di = 0; di < 4; ++di) a4[di] = *(const float4*)&At[(i0 + di) * 128 + m];
      #pragma unroll
      for (int dm = 0; dm < 4; ++dm){
        float xv[5];
        #pragma unroll
        for (int dc = 0; dc < 5; ++dc) xv[dc] = xf[(m + dm) * 40 + c0 + dc];
        #pragma unroll
        for (int di = 0; di < 4; ++di){
          float av = (&a4[di].x)[dm];
          #pragma unroll
          for (int dc = 0; dc < 5; ++dc)
            acc[di][dc] = fmaf(av, xv[dc], acc[di][dc]);
        }
      }
    }
    #pragma unroll
    for (int di = 0; di < 4; ++di)
      #pragma unroll
      for (int dc = 0; dc < 5; ++dc)
        M2[(i0 + di) * 40 + c0 + dc] = acc[di][dc];
  }
  __syncthreads();

  // H_t[i][j] = leaky(bias[j] + sum_c M2[i][c]*w[c][j]); tile 16i x 4j
  {
    const int j0 = (t & 31) * 4, i0 = (t >> 5) * 16;
    float4 bv = *(const float4*)&bias[j0];
    float acc[16][4];
    #pragma unroll
    for (int di = 0; di < 16; ++di){ acc[di][0]=bv.x; acc[di][1]=bv.y; acc[di][2]=bv.z; acc[di][3]=bv.w; }
    for (int c = 0; c < 40; ++c){
      float4 wv = *(const float4*)&w[c * 128 + j0];
      #pragma unroll
      for (int di = 0; di < 16; ++di){
        float mv = M2[(i0 + di) * 40 + c];
        acc[di][0] = fmaf(mv, wv.x, acc[di][0]);
        acc[di][1] = fmaf(mv, wv.y, acc[di][1]);
        acc[di][2] = fmaf(mv, wv.z, acc[di][2]);
        acc[di][3] = fmaf(mv, wv.w, acc[di][3]);
      }
    }
    float* dst = H + (size_t)b * (N * HG) + 40 * 128;
    #pragma unroll
    for (int di = 0; di < 16; ++di){
      float4 o;
      o.x = (acc[di][0] >= 0.f) ? acc[di][0] : 0.01f * acc[di][0];
      o.y = (acc[di][1] >= 0.f) ? acc[di][1] : 0.01f * acc[di][1];
      o.z = (acc[di][2] >= 0.f) ? acc[di][2] : 0.01f * acc[di][2];
      o.w = (acc[di][3] >= 0.f) ? acc[di][3] : 0.01f * acc[di][3];
      *(float4*)&dst[(i0 + di) * 128 + j0] = o;
    }
  }
}

__global__ void initout_kernel(float* __restrict__ out, const float* __restrict__ fcb){
  int i = blockIdx.x * 256 + threadIdx.x;
  if (i < BSZ) out[i] = fcb[0];
}

// ---------- prep: per-head M^T, Wv^T, c1/c2/c3; sliced over 8 blocks/head ----------
__global__ __launch_bounds__(256) void prep_kernel(
    const float* __restrict__ qw, const float* __restrict__ qb,
    const float* __restrict__ kw, const float* __restrict__ kb,
    const float* __restrict__ vw,
    short* __restrict__ MT, short* __restrict__ WvT,
    float* __restrict__ c1, float* __restrict__ c2, float* __restrict__ c3){
  const int h = blockIdx.x, sl = blockIdx.y, t = threadIdx.x;
  const float* Q = qw + h * 16384;
  const float* K = kw + h * 16384;
  const float* V = vw + h * 16384;
  for (int idx = t; idx < 2048; idx += 256){
    int j = sl * 16 + (idx >> 7), d = idx & 127;
    float acc = 0.f;
    for (int e = 0; e < 128; ++e) acc = fmaf(Q[d * 128 + e], K[j * 128 + e], acc);
    MT[h * 16384 + j * 128 + d] = (short)f2bf(acc);     // MT[j][d] = M[d][j]
  }
  for (int idx = t; idx < 2048; idx += 256){
    int e = sl * 16 + (idx >> 7), d = idx & 127;
    WvT[h * 16384 + e * 128 + d] = (short)f2bf(V[d * 128 + e]);
  }
  if (t < 16){
    int r = sl * 16 + t;
    float a = 0.f, bsum = 0.f;
    for (int e = 0; e < 128; ++e){
      a    = fmaf(Q[r * 128 + e], kb[h * 128 + e], a);
      bsum = fmaf(K[r * 128 + e], qb[h * 128 + e], bsum);
    }
    c1[h * 128 + r] = a;
    c2[h * 128 + r] = bsum;
  }
  if (t == 16 && sl == 0){
    float a = 0.f;
    for (int e = 0; e < 128; ++e) a = fmaf(qb[h * 128 + e], kb[h * 128 + e], a);
    c3[h] = a;
  }
}

// ---------- cast H -> bf16 with zero-padded rows 168..175 ----------
__global__ __launch_bounds__(256) void cast_kernel(const float* __restrict__ H,
                                                   short* __restrict__ Hbf){
  const int b = blockIdx.x;
  for (int idx = threadIdx.x; idx < NPAD * 128; idx += 256){
    int n = idx >> 7, d = idx & 127;
    float v = (n < N) ? H[((size_t)b * N + n) * 128 + d] : 0.f;
    Hbf[(size_t)b * NPAD * 128 + idx] = (short)f2bf(v);
  }
}

// ---------- transpose Hbf -> HbT [e][m], m padded to 192 with zeros ----------
__global__ __launch_bounds__(256) void castT_kernel(const short* __restrict__ Hbf,
                                                    short* __restrict__ HbT){
  const int b = blockIdx.x;
  __shared__ short tile[176 * 130];
  const short* src = Hbf + (size_t)b * NPAD * 128;
  for (int idx = threadIdx.x; idx < 176 * 128; idx += 256){
    int m = idx >> 7, e = idx & 127;
    tile[m * 130 + e] = src[idx];
  }
  __syncthreads();
  short* dst = HbT + (size_t)b * 128 * 192;
  for (int idx = threadIdx.x; idx < 128 * 192; idx += 256){
    int e = idx / 192, m = idx - e * 192;
    dst[idx] = (m < 176) ? tile[m * 130 + e] : (short)0;
  }
}

// ---------- u1/u2 precompute: u1[n]=H[n]·c1, u2[n]=H[n]·c2 per (b,h) ----------
__global__ __launch_bounds__(256) void uprep_kernel(const short* __restrict__ Hbf,
    const float* __restrict__ c1, const float* __restrict__ c2,
    float* __restrict__ u1g, float* __restrict__ u2g){
  const int b = blockIdx.x, t = threadIdx.x;
  for (int idx = t; idx < 176 * 4; idx += 256){
    int n = idx >> 2, h = idx & 3;
    const bf16x8* rp = (const bf16x8*)(Hbf + (size_t)b * NPAD * 128 + (size_t)n * 128);
    const float* C1 = c1 + h * 128;
    const float* C2 = c2 + h * 128;
    float a1 = 0.f, a2 = 0.f;
    for (int kk = 0; kk < 16; ++kk){
      bf16x8 v = rp[kk];
      #pragma unroll
      for (int j = 0; j < 8; ++j){
        float hv = bf2f((unsigned short)v[j]);
        a1 = fmaf(hv, C1[kk * 8 + j], a1);
        a2 = fmaf(hv, C2[kk * 8 + j], a2);
      }
    }
    u1g[(size_t)(b * 4 + h) * 176 + n] = a1;
    u2g[(size_t)(b * 4 + h) * 176 + n] = a2;
  }
}

// ---------- attention mega-kernel: grid (b, h, z), z=0..3 row chunks ----------
__global__ __launch_bounds__(256) void attn_mega(
    const short* __restrict__ Hbf, const short* __restrict__ HbT,
    const short* __restrict__ MT, const short* __restrict__ WvT,
    const float* __restrict__ u1g, const float* __restrict__ u2g,
    const float* __restrict__ c3g, const float* __restrict__ vb,
    const float* __restrict__ fcw, float* __restrict__ out){
  const int b = blockIdx.x, h = blockIdx.y, z = blockIdx.z;
  const int NT = (z < 3) ? 3 : 2;
  const int rows = NT * 16;
  const int rowbase = z * 48;
  const int t = threadIdx.x;
  const int w = t >> 6, l = t & 63, quad = l >> 4, l15 = l & 15;

  __shared__ __align__(16) short Tsh[48 * 128];       // T then U (XOR-swizzled)
  __shared__ __align__(16) short Ssh[48 * 184 + 16];  // S then P (bf16, stride 184)
  __shared__ float u1s[48];
  __shared__ float u2s[176];
  __shared__ float red4[4];

  const short* Hb   = Hbf + (size_t)b * NPAD * 128;
  const short* HT   = HbT + (size_t)b * 128 * 192;
  const short* MTh  = MT + h * 16384;
  const short* WvTh = WvT + h * 16384;
  const float c3v = c3g[h];
  const float inv = 0.08838834764831845f;   // 1/sqrt(128)

  if (t < 176) u2s[t] = u2g[(size_t)(b * 4 + h) * 176 + t];
  if (t < rows) u1s[t] = u1g[(size_t)(b * 4 + h) * 176 + rowbase + t];

  // ---- Phase A: T = H_rows @ M  (write bf16, XOR-swizzled) ----
  for (int jt = 0; jt < 2; ++jt){
    const int j0 = (w * 2 + jt) * 16;
    bf16x8 B[4];
    #pragma unroll
    for (int kk = 0; kk < 4; ++kk)
      B[kk] = *(const bf16x8*)(MTh + (j0 + l15) * 128 + kk * 32 + quad * 8);
    for (int nt = 0; nt < NT; ++nt){
      f32x4 acc = {0.f, 0.f, 0.f, 0.f};
      #pragma unroll
      for (int kk = 0; kk < 4; ++kk){
        bf16x8 A = *(const bf16x8*)(Hb + (size_t)(rowbase + nt * 16 + l15) * 128 + kk * 32 + quad * 8);
        acc = __builtin_amdgcn_mfma_f32_16x16x32_bf16(A, B[kk], acc, 0, 0, 0);
      }
      const int jcol = j0 + l15, ch = jcol >> 3;
      #pragma unroll
      for (int r = 0; r < 4; ++r){
        int row = nt * 16 + quad * 4 + r;
        Tsh[row * 128 + ((ch ^ (row & 15)) << 3) + (jcol & 7)] = (short)f2bf(acc[r]);
      }
    }
  }
  __syncthreads();

  // ---- Phase B: S = T @ H^T (+rank-1 terms), bf16 into Ssh ----
  for (int mi = 0; mi < 3; ++mi){
    const int mt = w + mi * 4;
    if (mt >= 11) break;
    const int m0 = mt * 16;
    bf16x8 B[4];
    #pragma unroll
    for (int kk = 0; kk < 4; ++kk)
      B[kk] = *(const bf16x8*)(Hb + (size_t)(m0 + l15) * 128 + kk * 32 + quad * 8);
    const int m = m0 + l15;
    const float u2v = u2s[m];
    for (int nt = 0; nt < NT; ++nt){
      f32x4 acc = {0.f, 0.f, 0.f, 0.f};
      #pragma unroll
      for (int kk = 0; kk < 4; ++kk){
        int row = nt * 16 + l15;
        bf16x8 A = *(const bf16x8*)(&Tsh[row * 128 + (((kk * 4 + quad) ^ l15) << 3)]);
        acc = __builtin_amdgcn_mfma_f32_16x16x32_bf16(A, B[kk], acc, 0, 0, 0);
      }
      #pragma unroll
      for (int r = 0; r < 4; ++r){
        int nl = nt * 16 + quad * 4 + r;
        float s = (acc[r] + u1s[nl] + u2v + c3v) * inv;
        Ssh[nl * 184 + m] = (short)f2bf(s);
      }
    }
  }
  __syncthreads();

  // ---- softmax: one row per wave pass; cols 0..167 valid, 168..175 -> 0 ----
  {
    const int nrw = NT * 4;                 // rows per wave
    for (int rr = 0; rr < nrw; ++rr){
      const int r = w * nrw + rr;
      short* rowp = &Ssh[r * 184];
      float v0 = bf2f((unsigned short)rowp[l]);
      float v1 = bf2f((unsigned short)rowp[64 + l]);
      float v2 = (l < 40) ? bf2f((unsigned short)rowp[128 + l]) : -1e30f;
      float mv = wmax(fmaxf(fmaxf(v0, v1), v2));
      float e0 = __expf(v0 - mv);
      float e1 = __expf(v1 - mv);
      float e2 = (l < 40) ? __expf(v2 - mv) : 0.f;
      float sinv = 1.f / wsum(e0 + e1 + e2);
      rowp[l]      = (short)f2bf(e0 * sinv);
      rowp[64 + l] = (short)f2bf(e1 * sinv);
      if (l < 56) rowp[128 + l] = (l < 40) ? (short)f2bf(e2 * sinv) : (short)0;
    }
  }
  __syncthreads();

  // ---- Phase C: U = P @ H  (B from transposed HbT; write U into Tsh swizzled) ----
  for (int ei = 0; ei < 2; ++ei){
    const int e0 = (w * 2 + ei) * 16;
    bf16x8 B[6];
    #pragma unroll
    for (int kt = 0; kt < 6; ++kt)
      B[kt] = *(const bf16x8*)(HT + (size_t)(e0 + l15) * 192 + kt * 32 + quad * 8);
    for (int nt = 0; nt < NT; ++nt){
      f32x4 acc = {0.f, 0.f, 0.f, 0.f};
      #pragma unroll
      for (int kt = 0; kt < 6; ++kt){
        bf16x8 A = {0, 0, 0, 0, 0, 0, 0, 0};
        if (kt != 5 || quad < 2)
          A = *(const bf16x8*)(&Ssh[(nt * 16 + l15) * 184 + kt * 32 + quad * 8]);
        acc = __builtin_amdgcn_mfma_f32_16x16x32_bf16(A, B[kt], acc, 0, 0, 0);
      }
      const int ecol = e0 + l15, ch = ecol >> 3;
      #pragma unroll
      for (int r = 0; r < 4; ++r){
        int row = nt * 16 + quad * 4 + r;
        Tsh[row * 128 + ((ch ^ (row & 15)) << 3) + (ecol & 7)] = (short)f2bf(acc[r]);
      }
    }
  }
  __syncthreads();

  // ---- Phase D: O = U @ Wv + vb, fused FC reduction ----
  float tp = 0.f;
  for (int ei = 0; ei < 2; ++ei){
    const int e0 = (w * 2 + ei) * 16;
    bf16x8 B[4];
    #pragma unroll
    for (int kk = 0; kk < 4; ++kk)
      B[kk] = *(const bf16x8*)(WvTh + (e0 + l15) * 128 + kk * 32 + quad * 8);
    const float vbv = vb[h * 128 + e0 + l15];
    for (int nt = 0; nt < NT; ++nt){
      f32x4 acc = {0.f, 0.f, 0.f, 0.f};
      #pragma unroll
      for (int kk = 0; kk < 4; ++kk){
        int row = nt * 16 + l15;
        bf16x8 A = *(const bf16x8*)(&Tsh[row * 128 + (((kk * 4 + quad) ^ l15) << 3)]);
        acc = __builtin_amdgcn_mfma_f32_16x16x32_bf16(A, B[kk], acc, 0, 0, 0);
      }
      #pragma unroll
      for (int r = 0; r < 4; ++r){
        int ng = rowbase + nt * 16 + quad * 4 + r;
        if (ng < N)
          tp = fmaf(acc[r] + vbv, fcw[ng * 512 + h * 128 + e0 + l15], tp);
      }
    }
  }
  float tot = rsum256(tp, red4);
  if (t == 0) atomicAdd(out + b, tot);
}

} // anonymous namespace

extern "C" void kernel_launch(void* const* d_in, const int* in_sizes, int n_in,
                              void* d_out, int out_size, void* d_ws, size_t ws_size,
                              hipStream_t stream) {
  (void)in_sizes; (void)n_in; (void)out_size;
  const float* X      = (const float*)d_in[0];
  const float* spa_w1 = (const float*)d_in[1];
  const float* spa_b1 = (const float*)d_in[2];
  const float* spa_w2 = (const float*)d_in[3];
  const float* spa_b2 = (const float*)d_in[4];
  const float* tem_w1 = (const float*)d_in[5];
  const float* tem_b1 = (const float*)d_in[6];
  const float* tem_w2 = (const float*)d_in[7];
  const float* tem_b2 = (const float*)d_in[8];
  const float* sgnn_w = (const float*)d_in[9];
  const float* sgnn_b = (const float*)d_in[10];
  const float* tgnn_w = (const float*)d_in[11];
  const float* tgnn_b = (const float*)d_in[12];
  const float* q_w    = (const float*)d_in[13];
  const float* q_b    = (const float*)d_in[14];
  const float* k_w    = (const float*)d_in[15];
  const float* k_b    = (const float*)d_in[16];
  const float* v_w    = (const float*)d_in[17];
  const float* v_b    = (const float*)d_in[18];
  const float* fc_w   = (const float*)d_in[19];
  const float* fc_b   = (const float*)d_in[20];
  float* out = (float*)d_out;

  // ws layout (bytes): same as round 4 (182,714,368 total)
  if (ws_size < (size_t)182714368) return;

  char* wsb = (char*)d_ws;
  float* H   = (float*)wsb;
  short* HbT = (short*)wsb;
  float* u1g = (float*)(wsb + 50331648);
  float* u2g = (float*)(wsb + 53215232);
  char*  Rb  = wsb + 88080384;
  float* Xf  = (float*)Rb;
  float* As  = (float*)(Rb + 20971520);
  float* At  = (float*)(Rb + 27525120);
  short* Hbf = (short*)Rb;
  char*  Pb  = Rb + 46137344;
  short* MT  = (short*)Pb;
  short* WvT = (short*)(Pb + 131072);
  float* c1  = (float*)(Pb + 262144);
  float* c2  = (float*)(Pb + 264192);
  float* c3  = (float*)(Pb + 266240);

  feat_kernel<<<BSZ * P / 4, 256, 0, stream>>>(X, Xf);
  cumnorm_kernel<<<BSZ, 256, 0, stream>>>(Xf);
  adjt_kernel<<<BSZ, 256, 0, stream>>>(Xf, tem_w1, tem_b1, tem_w2, tem_b2, At);
  adjs_kernel<<<BSZ, 256, 0, stream>>>(Xf, spa_w1, spa_b1, spa_w2, spa_b2, As);
  hs_kernel<<<BSZ, 256, 0, stream>>>(Xf, As, sgnn_w, sgnn_b, H);
  ht_kernel<<<BSZ, 256, 0, stream>>>(Xf, At, tgnn_w, tgnn_b, H);
  prep_kernel<<<dim3(NH, 8), 256, 0, stream>>>(q_w, q_b, k_w, k_b, v_w, MT, WvT, c1, c2, c3);
  cast_kernel<<<BSZ, 256, 0, stream>>>(H, Hbf);          // H fp32 dead after this
  castT_kernel<<<BSZ, 256, 0, stream>>>(Hbf, HbT);       // writes into dead-H region
  uprep_kernel<<<BSZ, 256, 0, stream>>>(Hbf, c1, c2, u1g, u2g);
  initout_kernel<<<4, 256, 0, stream>>>(out, fc_b);
  attn_mega<<<dim3(BSZ, NH, 4), 256, 0, stream>>>(Hbf, HbT, MT, WvT, u1g, u2g, c3, v_b, fc_w, out);
}